// Round 3
// baseline (7330.720 us; speedup 1.0000x reference)
//
#include <hip/hip_runtime.h>
#include <hip/hip_bf16.h>
#include <math.h>

typedef __hip_bfloat16 bf16;

#define NB 4096          // batch rows
#define DM 768           // model dim
#define CH 1024          // attention row-chunk

__device__ __forceinline__ float cvt(float x){ return x; }
__device__ __forceinline__ float cvt(bf16 x){ return __bfloat162float(x); }
__device__ __forceinline__ void stv(float* p, float v){ *p = v; }
__device__ __forceinline__ void stv(bf16* p, float v){ *p = __float2bfloat16(v); }

__device__ __forceinline__ float gelu_f(float x){
    return 0.5f * x * (1.0f + erff(x * 0.70710678118654752440f));
}
__device__ __forceinline__ float sigmoid_f(float x){
    return 1.0f / (1.0f + expf(-x));
}

// ---------------------------------------------------------------------------
// Generic fused GEMM: C[M,N] = act((A @ B' + bias0) * alpha * g + bias1)
//   BLAYOUT 0: Bm is (N,K) row-major  -> out = A @ Bm^T
//   BLAYOUT 1: Bm is (K,N) row-major  -> out = A @ Bm
// act: 0 none, 1 gelu(exact), 2 sigmoid, 3 relu
// ---------------------------------------------------------------------------
template<typename TA, typename TB, typename TC, int BLAYOUT>
__global__ __launch_bounds__(256) void gemm_k(
    const TA* __restrict__ A, const TB* __restrict__ Bm, TC* __restrict__ C,
    int M, int N, int K,
    const float* __restrict__ bias0, float alpha, const float* __restrict__ gvec,
    const float* __restrict__ bias1, int act)
{
    constexpr int LDT = 68;               // padded LDS stride
    __shared__ float As[16 * LDT];
    __shared__ float Bs[16 * LDT];
    const int tid = threadIdx.x;
    const int tx  = tid & 15;
    const int ty  = tid >> 4;
    const int row0 = blockIdx.y * 64;
    const int col0 = blockIdx.x * 64;

    float acc[4][4] = {};
    const int nK = (K + 15) >> 4;
    for (int kt = 0; kt < nK; ++kt){
        const int k0 = kt << 4;
        {   // A tile: As[k][m]
            const int k  = tid & 15;
            const int kg = k0 + k;
            #pragma unroll
            for (int i = 0; i < 4; ++i){
                const int m  = (tid >> 4) + i * 16;
                const int mg = row0 + m;
                float v = 0.f;
                if (mg < M && kg < K) v = cvt(A[(size_t)mg * K + kg]);
                As[k * LDT + m] = v;
            }
        }
        if (BLAYOUT == 0){
            const int k  = tid & 15;
            const int kg = k0 + k;
            #pragma unroll
            for (int i = 0; i < 4; ++i){
                const int n  = (tid >> 4) + i * 16;
                const int ng = col0 + n;
                float v = 0.f;
                if (ng < N && kg < K) v = cvt(Bm[(size_t)ng * K + kg]);
                Bs[k * LDT + n] = v;
            }
        } else {
            const int n  = tid & 63;
            const int ng = col0 + n;
            #pragma unroll
            for (int i = 0; i < 4; ++i){
                const int k  = (tid >> 6) + i * 4;
                const int kg = k0 + k;
                float v = 0.f;
                if (ng < N && kg < K) v = cvt(Bm[(size_t)kg * N + ng]);
                Bs[k * LDT + n] = v;
            }
        }
        __syncthreads();
        #pragma unroll
        for (int kk = 0; kk < 16; ++kk){
            const float4 av = *(const float4*)&As[kk * LDT + ty * 4];
            const float4 bv = *(const float4*)&Bs[kk * LDT + tx * 4];
            const float a4[4] = {av.x, av.y, av.z, av.w};
            const float b4[4] = {bv.x, bv.y, bv.z, bv.w};
            #pragma unroll
            for (int i = 0; i < 4; ++i)
                #pragma unroll
                for (int j = 0; j < 4; ++j)
                    acc[i][j] = fmaf(a4[i], b4[j], acc[i][j]);
        }
        __syncthreads();
    }
    #pragma unroll
    for (int j = 0; j < 4; ++j){
        const int cg = col0 + tx * 4 + j;
        if (cg >= N) continue;
        const float b0 = bias0 ? bias0[cg] : 0.f;
        const float gm = gvec  ? gvec[cg]  : 1.f;
        const float b1 = bias1 ? bias1[cg] : 0.f;
        #pragma unroll
        for (int i = 0; i < 4; ++i){
            const int rg = row0 + ty * 4 + i;
            if (rg >= M) continue;
            float v = (acc[i][j] + b0) * (alpha * gm) + b1;
            if      (act == 1) v = gelu_f(v);
            else if (act == 2) v = sigmoid_f(v);
            else if (act == 3) v = fmaxf(v, 0.f);
            stv(&C[(size_t)rg * N + cg], v);
        }
    }
}

// Extract center taps: fda_w1 (384,768,3,3)->[.,.,1,1] ; fda_sa_w (1,384,7,7)->[0,.,3,3]
__global__ __launch_bounds__(256) void extract_k(
    const float* __restrict__ w1, const float* __restrict__ saw,
    float* __restrict__ w1c, float* __restrict__ sac)
{
    const int idx = blockIdx.x * 256 + threadIdx.x;
    if (idx < 384 * 768){
        const int oc = idx / 768, ic = idx % 768;
        w1c[idx] = w1[(size_t)oc * 6912 + (size_t)ic * 9 + 4];
    }
    if (idx < 384) sac[idx] = saw[(size_t)idx * 49 + 24];
}

// FDA pointwise chain per row (IC=384), in place on x (bf16):
// x2=x1*ca; sa=sig(<x2,sac>+sab); x3=x2*sa; xg=gelu(<x3,decw>+decb); x4=x3+sigma*(x3-xg)
__global__ __launch_bounds__(128) void fda_pointwise_k(
    bf16* __restrict__ x, const bf16* __restrict__ ca,
    const float* __restrict__ sac, const float* __restrict__ sab,
    const float* __restrict__ decw, const float* __restrict__ decb,
    const float* __restrict__ sigma)
{
    __shared__ float red[128];
    const int b = blockIdx.x;
    const int tid = threadIdx.x;
    bf16* xr = x + (size_t)b * 384;
    const bf16* car = ca + (size_t)b * 384;
    float x2[3];
    float p = 0.f;
    #pragma unroll
    for (int i = 0; i < 3; ++i){
        const int c = tid + i * 128;
        const float v = cvt(xr[c]) * cvt(car[c]);
        x2[i] = v;
        p += v * sac[c];
    }
    red[tid] = p; __syncthreads();
    for (int s = 64; s > 0; s >>= 1){ if (tid < s) red[tid] += red[tid + s]; __syncthreads(); }
    const float sa = sigmoid_f(red[0] + sab[0]);
    __syncthreads();
    float q = 0.f;
    #pragma unroll
    for (int i = 0; i < 3; ++i){
        const int c = tid + i * 128;
        x2[i] *= sa;
        q += x2[i] * decw[c];
    }
    red[tid] = q; __syncthreads();
    for (int s = 64; s > 0; s >>= 1){ if (tid < s) red[tid] += red[tid + s]; __syncthreads(); }
    const float xg = gelu_f(red[0] + decb[0]);
    #pragma unroll
    for (int i = 0; i < 3; ++i){
        const int c = tid + i * 128;
        const float sg = sigma[c];
        stv(&xr[c], x2[i] + sg * (x2[i] - xg));
    }
}

// Row softmax over N columns, in place (bf16)
__global__ __launch_bounds__(256) void softmax_rows_k(bf16* __restrict__ S, int N)
{
    __shared__ float red[256];
    const int row = blockIdx.x;
    bf16* r = S + (size_t)row * N;
    const int tid = threadIdx.x;
    float m = -3.4e38f;
    for (int i = tid; i < N; i += 256) m = fmaxf(m, cvt(r[i]));
    red[tid] = m; __syncthreads();
    for (int s = 128; s > 0; s >>= 1){ if (tid < s) red[tid] = fmaxf(red[tid], red[tid + s]); __syncthreads(); }
    m = red[0]; __syncthreads();
    float sum = 0.f;
    float ev[16];
    int c = 0;
    for (int i = tid; i < N; i += 256){ const float e = expf(cvt(r[i]) - m); ev[c++] = e; sum += e; }
    red[tid] = sum; __syncthreads();
    for (int s = 128; s > 0; s >>= 1){ if (tid < s) red[tid] += red[tid + s]; __syncthreads(); }
    const float inv = 1.0f / red[0];
    c = 0;
    for (int i = tid; i < N; i += 256) stv(&r[i], ev[c++] * inv);
}

// acc (+)= sigmoid(gate) * a * scale[col]   (gate already sigmoided -> double sigmoid per ref)
__global__ __launch_bounds__(256) void combine_k(
    float* __restrict__ acc, const bf16* __restrict__ gate,
    const bf16* __restrict__ a, const float* __restrict__ scale, int init)
{
    const size_t idx = (size_t)blockIdx.x * 256 + threadIdx.x;
    if (idx >= (size_t)NB * DM) return;
    const int col = (int)(idx % DM);
    const float v = sigmoid_f(cvt(gate[idx])) * cvt(a[idx]) * scale[col];
    acc[idx] = init ? v : (acc[idx] + v);
}

// logits = acc @ cls_w.T + cls_b (768 -> 3), softmax(3), fp32 out. One wave per row.
__global__ __launch_bounds__(64) void cls_softmax_k(
    const float* __restrict__ acc, const float* __restrict__ w,
    const float* __restrict__ bias, float* __restrict__ out)
{
    const int b = blockIdx.x;
    const float* r = acc + (size_t)b * DM;
    float p0 = 0.f, p1 = 0.f, p2 = 0.f;
    for (int k = threadIdx.x; k < DM; k += 64){
        const float v = r[k];
        p0 = fmaf(v, w[k],        p0);
        p1 = fmaf(v, w[DM + k],   p1);
        p2 = fmaf(v, w[2*DM + k], p2);
    }
    #pragma unroll
    for (int off = 32; off > 0; off >>= 1){
        p0 += __shfl_down(p0, off, 64);
        p1 += __shfl_down(p1, off, 64);
        p2 += __shfl_down(p2, off, 64);
    }
    if (threadIdx.x == 0){
        const float l0 = p0 + bias[0];
        const float l1 = p1 + bias[1];
        const float l2 = p2 + bias[2];
        const float mx = fmaxf(l0, fmaxf(l1, l2));
        const float e0 = expf(l0 - mx), e1 = expf(l1 - mx), e2 = expf(l2 - mx);
        const float inv = 1.f / (e0 + e1 + e2);
        out[(size_t)b * 3 + 0] = e0 * inv;
        out[(size_t)b * 3 + 1] = e1 * inv;
        out[(size_t)b * 3 + 2] = e2 * inv;
    }
}

extern "C" void kernel_launch(void* const* d_in, const int* in_sizes, int n_in,
                              void* d_out, int out_size, void* d_ws, size_t ws_size,
                              hipStream_t stream)
{
    const float* text   = (const float*)d_in[0];
    const float* image  = (const float*)d_in[1];
    const float* tl_w   = (const float*)d_in[2];
    const float* tl_b   = (const float*)d_in[3];
    const float* il_w   = (const float*)d_in[4];
    const float* il_b   = (const float*)d_in[5];
    // d_in[6..9] (sda_wq/bq/wk/bk) are dead: seq_len=1 -> softmax over size-1 axis == 1
    const float* sda_wv = (const float*)d_in[10];
    const float* sda_bv = (const float*)d_in[11];
    const float* sda_wo = (const float*)d_in[12];
    const float* sda_bo = (const float*)d_in[13];
    const float* fda_w1 = (const float*)d_in[14];
    const float* fda_b1 = (const float*)d_in[15];
    const float* bn1_g  = (const float*)d_in[16];
    const float* bn1_b  = (const float*)d_in[17];
    const float* ca_w1  = (const float*)d_in[18];
    const float* ca_w2  = (const float*)d_in[19];
    const float* sa_w   = (const float*)d_in[20];
    const float* sa_b   = (const float*)d_in[21];
    const float* dec_w  = (const float*)d_in[22];
    const float* dec_b  = (const float*)d_in[23];
    const float* sigma  = (const float*)d_in[24];
    const float* fda_wf = (const float*)d_in[25];
    const float* fda_bf = (const float*)d_in[26];
    const float* bn2_g  = (const float*)d_in[27];
    const float* bn2_b  = (const float*)d_in[28];
    const float* dmi_wq = (const float*)d_in[29];
    const float* dmi_bq = (const float*)d_in[30];
    const float* dmi_wk = (const float*)d_in[31];
    const float* dmi_bk = (const float*)d_in[32];
    const float* dmi_wv = (const float*)d_in[33];
    const float* dmi_bv = (const float*)d_in[34];
    const float* tg_w1  = (const float*)d_in[35];
    const float* tg_b1  = (const float*)d_in[36];
    const float* tg_w2  = (const float*)d_in[37];
    const float* tg_b2  = (const float*)d_in[38];
    const float* ig_w1  = (const float*)d_in[39];
    const float* ig_b1  = (const float*)d_in[40];
    const float* ig_w2  = (const float*)d_in[41];
    const float* ig_b2  = (const float*)d_in[42];
    const float* t_scale= (const float*)d_in[43];
    const float* i_scale= (const float*)d_in[44];
    const float* cls_w  = (const float*)d_in[45];
    const float* cls_b  = (const float*)d_in[46];
    float* out = (float*)d_out;

    // ---- workspace layout (~62 MB total) ----
    char* base = (char*)d_ws;
    const size_t SLOT = (size_t)NB * DM;           // 3,145,728 elements
    float* w1c = (float*)base;                      base += 384 * 768 * sizeof(float);  // 1.18 MB
    float* sac = (float*)base;                      base += 1024 * sizeof(float);
    float* ACC = (float*)base;                      base += SLOT * sizeof(float);       // 12.6 MB
    bf16* B0 = (bf16*)base;                         base += SLOT * sizeof(bf16);        // 6.3 MB each
    bf16* B1 = (bf16*)base;                         base += SLOT * sizeof(bf16);
    bf16* B2 = (bf16*)base;                         base += SLOT * sizeof(bf16);
    bf16* B3 = (bf16*)base;                         base += SLOT * sizeof(bf16);
    bf16* B4 = (bf16*)base;                         base += SLOT * sizeof(bf16);
    bf16* B5 = (bf16*)base;                         base += SLOT * sizeof(bf16);
    bf16* SCc = (bf16*)base;                        base += (size_t)CH * NB * sizeof(bf16); // 8.4 MB

    const float bnscale = 1.0f / sqrtf(1.0f + 1e-5f);
    const float iscale  = 1.0f / sqrtf(768.0f);
    const dim3 blk(256);
    auto grid2 = [](int M, int N){ return dim3((N + 63) / 64, (M + 63) / 64); };

    extract_k<<<dim3((384 * 768 + 255) / 256), blk, 0, stream>>>(fda_w1, sa_w, w1c, sac);

    // t0 = gelu(text @ tl_w^T + tl_b) -> B0 ; im0 -> B1
    gemm_k<float, float, bf16, 0><<<grid2(NB, DM), blk, 0, stream>>>(text,  tl_w, B0, NB, DM, DM, tl_b, 1.f, nullptr, nullptr, 1);
    gemm_k<float, float, bf16, 0><<<grid2(NB, DM), blk, 0, stream>>>(image, il_w, B1, NB, DM, DM, il_b, 1.f, nullptr, nullptr, 1);

    // degenerate self-attn: t1 = (t0 @ wv^T + bv) @ wo^T + bo -> B3
    gemm_k<bf16, float, bf16, 0><<<grid2(NB, 512), blk, 0, stream>>>(B0, sda_wv, B2, NB, 512, DM, sda_bv, 1.f, nullptr, nullptr, 0);
    gemm_k<bf16, float, bf16, 0><<<grid2(NB, DM),  blk, 0, stream>>>(B2, sda_wo, B3, NB, DM, 512, sda_bo, 1.f, nullptr, nullptr, 0);

    // FDA: x1 = gelu((im0 @ w1c^T + b1)*bnscale*g1 + bb1) -> B0 (B,384)
    gemm_k<bf16, float, bf16, 0><<<grid2(NB, 384), blk, 0, stream>>>(B1, w1c, B0, NB, 384, DM, fda_b1, bnscale, bn1_g, bn1_b, 1);
    // ca1 = gelu(x1 @ ca_w1^T) -> B2 (B,24); ca2 = sigmoid(ca1 @ ca_w2^T) -> B4 (B,384)
    gemm_k<bf16, float, bf16, 0><<<grid2(NB, 24),  blk, 0, stream>>>(B0, ca_w1, B2, NB, 24, 384, nullptr, 1.f, nullptr, nullptr, 1);
    gemm_k<bf16, float, bf16, 0><<<grid2(NB, 384), blk, 0, stream>>>(B2, ca_w2, B4, NB, 384, 24, nullptr, 1.f, nullptr, nullptr, 2);
    // pointwise chain (in place on B0)
    fda_pointwise_k<<<dim3(NB), dim3(128), 0, stream>>>(B0, B4, sac, sa_b, dec_w, dec_b, sigma);
    // im1 = gelu((x4 @ wf^T + bf)*bnscale*g2 + bb2) -> B1
    gemm_k<bf16, float, bf16, 0><<<grid2(NB, DM), blk, 0, stream>>>(B0, fda_wf, B1, NB, DM, 384, fda_bf, bnscale, bn2_g, bn2_b, 1);

    for (int d = 0; d < 2; ++d){
        const bf16* qsrc = d == 0 ? B3 : B1;   // t1 : im1
        const bf16* kvsrc= d == 0 ? B1 : B3;   // im1 : t1
        const float* gw1 = d == 0 ? tg_w1 : ig_w1;
        const float* gb1 = d == 0 ? tg_b1 : ig_b1;
        const float* gw2 = d == 0 ? tg_w2 : ig_w2;
        const float* gb2 = d == 0 ? tg_b2 : ig_b2;
        const float* sc  = d == 0 ? t_scale : i_scale;
        // q -> B0, k -> B2, v -> B4
        gemm_k<bf16, float, bf16, 0><<<grid2(NB, DM), blk, 0, stream>>>(qsrc,  dmi_wq, B0, NB, DM, DM, dmi_bq, 1.f, nullptr, nullptr, 0);
        gemm_k<bf16, float, bf16, 0><<<grid2(NB, DM), blk, 0, stream>>>(kvsrc, dmi_wk, B2, NB, DM, DM, dmi_bk, 1.f, nullptr, nullptr, 0);
        gemm_k<bf16, float, bf16, 0><<<grid2(NB, DM), blk, 0, stream>>>(kvsrc, dmi_wv, B4, NB, DM, DM, dmi_bv, 1.f, nullptr, nullptr, 0);
        // attention in row-chunks: a -> B5
        for (int c = 0; c < NB / CH; ++c){
            const bf16* qc = B0 + (size_t)c * CH * DM;
            bf16*       ac = B5 + (size_t)c * CH * DM;
            gemm_k<bf16, bf16, bf16, 0><<<grid2(CH, NB), blk, 0, stream>>>(qc, B2, SCc, CH, NB, DM, nullptr, iscale, nullptr, nullptr, 0);
            softmax_rows_k<<<dim3(CH), blk, 0, stream>>>(SCc, NB);
            gemm_k<bf16, bf16, bf16, 1><<<grid2(CH, DM), blk, 0, stream>>>(SCc, B4, ac, CH, DM, NB, nullptr, 1.f, nullptr, nullptr, 0);
        }
        // gate = sigmoid(relu(a@gw1^T+gb1)@gw2^T+gb2): B0 (q dead), then B2 (k dead)
        gemm_k<bf16, float, bf16, 0><<<grid2(NB, DM), blk, 0, stream>>>(B5, gw1, B0, NB, DM, DM, gb1, 1.f, nullptr, nullptr, 3);
        gemm_k<bf16, float, bf16, 0><<<grid2(NB, DM), blk, 0, stream>>>(B0, gw2, B2, NB, DM, DM, gb2, 1.f, nullptr, nullptr, 2);
        combine_k<<<dim3((NB * DM + 255) / 256), blk, 0, stream>>>(ACC, B2, B5, sc, d == 0 ? 1 : 0);
    }

    cls_softmax_k<<<dim3(NB), dim3(64), 0, stream>>>(ACC, cls_w, cls_b, out);
}

// Round 4
// 1196.141 us; speedup vs baseline: 6.1286x; 6.1286x over previous
//
#include <hip/hip_runtime.h>
#include <hip/hip_bf16.h>
#include <math.h>

typedef __hip_bfloat16 bf16;
typedef __bf16 bf16x8 __attribute__((ext_vector_type(8)));
typedef float f32x4 __attribute__((ext_vector_type(4)));

#define NB 4096          // batch rows
#define DM 768           // model dim
#define CH 2048          // attention row-chunk

__device__ __forceinline__ float cvt(float x){ return x; }
__device__ __forceinline__ float cvt(bf16 x){ return __bfloat162float(x); }
__device__ __forceinline__ void stv(float* p, float v){ *p = v; }
__device__ __forceinline__ void stv(bf16* p, float v){ *p = __float2bfloat16(v); }

__device__ __forceinline__ float gelu_f(float x){
    return 0.5f * x * (1.0f + erff(x * 0.70710678118654752440f));
}
__device__ __forceinline__ float sigmoid_f(float x){
    return 1.0f / (1.0f + expf(-x));
}

__device__ __forceinline__ void async_copy16(const void* g, void* l){
    __builtin_amdgcn_global_load_lds((const __attribute__((address_space(1))) void*)g,
                                     (__attribute__((address_space(3))) void*)l, 16, 0, 0);
}

// ---------------------------------------------------------------------------
// MFMA GEMM: C = act((A @ Bm^T + bias0) * alpha * gvec + bias1)
// A: (M,K) bf16 row-major. Bm: (N,K) bf16 row-major (B^T layout).
// REQUIRES: M%128==0, N%128==0, K%32==0, 16B-aligned pointers.
// TRANS=1: store C^T into a (N,M) buffer (used to produce V^T for PV).
// m97 structure: 128x128 tile, 4 waves x (64x64), BK=32, global_load_lds w=16.
// ---------------------------------------------------------------------------
template<typename TC, int TRANS>
__global__ __launch_bounds__(256) void mgemm_k(
    const bf16* __restrict__ A, const bf16* __restrict__ Bm, TC* __restrict__ C,
    int M, int N, int K,
    const float* __restrict__ bias0, float alpha, const float* __restrict__ gvec,
    const float* __restrict__ bias1, int act)
{
    __shared__ __align__(16) bf16 Asl[128 * 32];
    __shared__ __align__(16) bf16 Bsl[128 * 32];
    const int tid  = threadIdx.x;
    const int wave = tid >> 6;
    const int lane = tid & 63;
    const int row0 = blockIdx.y * 128;
    const int col0 = blockIdx.x * 128;
    const int wrow = (wave & 1) * 64;
    const int wcol = (wave >> 1) * 64;
    const int fl   = lane & 15;            // m/n index within 16x16 tile
    const int ko   = (lane >> 4) * 8;      // k offset within BK=32
    const int srow = (lane >> 2);          // staging row within 16-row group
    const int scol = (lane & 3) * 8;       // staging col (elements)

    f32x4 acc[4][4] = {};

    for (int k0 = 0; k0 < K; k0 += 32){
        #pragma unroll
        for (int j = 0; j < 2; ++j){
            const int r = wave * 32 + j * 16 + srow;
            const bf16* srcA = A  + (size_t)(row0 + r) * K + k0 + scol;
            const bf16* srcB = Bm + (size_t)(col0 + r) * K + k0 + scol;
            // LDS dest: wave-uniform base + lane*16B (row-major 128x32, no pad)
            async_copy16(srcA, &Asl[(wave * 32 + j * 16) * 32]);
            async_copy16(srcB, &Bsl[(wave * 32 + j * 16) * 32]);
        }
        __syncthreads();
        bf16x8 af[4], bfv[4];
        #pragma unroll
        for (int i = 0; i < 4; ++i){
            af[i]  = *(const bf16x8*)&Asl[(wrow + i * 16 + fl) * 32 + ko];
            bfv[i] = *(const bf16x8*)&Bsl[(wcol + i * 16 + fl) * 32 + ko];
        }
        #pragma unroll
        for (int mi = 0; mi < 4; ++mi)
            #pragma unroll
            for (int ni = 0; ni < 4; ++ni)
                acc[mi][ni] = __builtin_amdgcn_mfma_f32_16x16x32_bf16(af[mi], bfv[ni], acc[mi][ni], 0, 0, 0);
        __syncthreads();
    }

    // C/D layout (verified m89/m91): col = lane&15, row = (lane>>4)*4 + reg
    #pragma unroll
    for (int ni = 0; ni < 4; ++ni){
        const int col = col0 + wcol + ni * 16 + fl;
        const float b0 = bias0 ? bias0[col] : 0.f;
        const float gm = (gvec ? gvec[col] : 1.f) * alpha;
        const float b1 = bias1 ? bias1[col] : 0.f;
        #pragma unroll
        for (int mi = 0; mi < 4; ++mi){
            const int rbase = row0 + wrow + mi * 16 + (lane >> 4) * 4;
            #pragma unroll
            for (int r = 0; r < 4; ++r){
                float v = (acc[mi][ni][r] + b0) * gm + b1;
                if      (act == 1) v = gelu_f(v);
                else if (act == 2) v = sigmoid_f(v);
                else if (act == 3) v = fmaxf(v, 0.f);
                if (TRANS) stv(&C[(size_t)col * M + rbase + r], v);
                else       stv(&C[(size_t)(rbase + r) * N + col], v);
            }
        }
    }
}

// ---------------------------------------------------------------------------
// VALU fallback GEMM (for tiny/odd shapes: K=24 or N=24 channel attention)
// C[M,N] = act((A @ Bm^T + bias0) * alpha * g + bias1); Bm is (N,K)
// ---------------------------------------------------------------------------
template<typename TA, typename TB, typename TC>
__global__ __launch_bounds__(256) void gemm_k(
    const TA* __restrict__ A, const TB* __restrict__ Bm, TC* __restrict__ C,
    int M, int N, int K,
    const float* __restrict__ bias0, float alpha, const float* __restrict__ gvec,
    const float* __restrict__ bias1, int act)
{
    constexpr int LDT = 68;
    __shared__ float As[16 * LDT];
    __shared__ float Bs[16 * LDT];
    const int tid = threadIdx.x;
    const int tx  = tid & 15;
    const int ty  = tid >> 4;
    const int row0 = blockIdx.y * 64;
    const int col0 = blockIdx.x * 64;

    float acc[4][4] = {};
    const int nK = (K + 15) >> 4;
    for (int kt = 0; kt < nK; ++kt){
        const int k0 = kt << 4;
        {
            const int k  = tid & 15;
            const int kg = k0 + k;
            #pragma unroll
            for (int i = 0; i < 4; ++i){
                const int m  = (tid >> 4) + i * 16;
                const int mg = row0 + m;
                float v = 0.f;
                if (mg < M && kg < K) v = cvt(A[(size_t)mg * K + kg]);
                As[k * LDT + m] = v;
            }
        }
        {
            const int k  = tid & 15;
            const int kg = k0 + k;
            #pragma unroll
            for (int i = 0; i < 4; ++i){
                const int n  = (tid >> 4) + i * 16;
                const int ng = col0 + n;
                float v = 0.f;
                if (ng < N && kg < K) v = cvt(Bm[(size_t)ng * K + kg]);
                Bs[k * LDT + n] = v;
            }
        }
        __syncthreads();
        #pragma unroll
        for (int kk = 0; kk < 16; ++kk){
            const float4 av = *(const float4*)&As[kk * LDT + ty * 4];
            const float4 bv = *(const float4*)&Bs[kk * LDT + tx * 4];
            const float a4[4] = {av.x, av.y, av.z, av.w};
            const float b4[4] = {bv.x, bv.y, bv.z, bv.w};
            #pragma unroll
            for (int i = 0; i < 4; ++i)
                #pragma unroll
                for (int j = 0; j < 4; ++j)
                    acc[i][j] = fmaf(a4[i], b4[j], acc[i][j]);
        }
        __syncthreads();
    }
    #pragma unroll
    for (int j = 0; j < 4; ++j){
        const int cg = col0 + tx * 4 + j;
        if (cg >= N) continue;
        const float b0 = bias0 ? bias0[cg] : 0.f;
        const float gm = (gvec ? gvec[cg] : 1.f) * alpha;
        const float b1 = bias1 ? bias1[cg] : 0.f;
        #pragma unroll
        for (int i = 0; i < 4; ++i){
            const int rg = row0 + ty * 4 + i;
            if (rg >= M) continue;
            float v = (acc[i][j] + b0) * gm + b1;
            if      (act == 1) v = gelu_f(v);
            else if (act == 2) v = sigmoid_f(v);
            else if (act == 3) v = fmaxf(v, 0.f);
            stv(&C[(size_t)rg * N + cg], v);
        }
    }
}

// Batched fp32 -> bf16 conversion (14 arrays, struct by value)
#define NCVT 14
struct CvtDesc { const float* s[NCVT]; bf16* d[NCVT]; int n[NCVT]; };
__global__ __launch_bounds__(256) void cvt_k(CvtDesc cd)
{
    const int e = blockIdx.y;
    const int base = (blockIdx.x * 256 + threadIdx.x) * 4;
    if (base >= cd.n[e]) return;
    const float4 v = *(const float4*)(cd.s[e] + base);
    union { bf16 h[4]; unsigned long long u; } o;
    o.h[0] = __float2bfloat16(v.x);
    o.h[1] = __float2bfloat16(v.y);
    o.h[2] = __float2bfloat16(v.z);
    o.h[3] = __float2bfloat16(v.w);
    *(unsigned long long*)(cd.d[e] + base) = o.u;
}

// Extract center taps: fda_w1 (384,768,3,3)->[.,.,1,1] (bf16); fda_sa_w (1,384,7,7)->[0,.,3,3] (fp32)
__global__ __launch_bounds__(256) void extract_k(
    const float* __restrict__ w1, const float* __restrict__ saw,
    bf16* __restrict__ w1c, float* __restrict__ sac)
{
    const int idx = blockIdx.x * 256 + threadIdx.x;
    if (idx < 384 * 768){
        const int oc = idx / 768, ic = idx % 768;
        w1c[idx] = __float2bfloat16(w1[(size_t)oc * 6912 + (size_t)ic * 9 + 4]);
    }
    if (idx < 384) sac[idx] = saw[(size_t)idx * 49 + 24];
}

// FDA pointwise chain per row (IC=384), in place on x (bf16)
__global__ __launch_bounds__(128) void fda_pointwise_k(
    bf16* __restrict__ x, const bf16* __restrict__ ca,
    const float* __restrict__ sac, const float* __restrict__ sab,
    const float* __restrict__ decw, const float* __restrict__ decb,
    const float* __restrict__ sigma)
{
    __shared__ float red[128];
    const int b = blockIdx.x;
    const int tid = threadIdx.x;
    bf16* xr = x + (size_t)b * 384;
    const bf16* car = ca + (size_t)b * 384;
    float x2[3];
    float p = 0.f;
    #pragma unroll
    for (int i = 0; i < 3; ++i){
        const int c = tid + i * 128;
        const float v = cvt(xr[c]) * cvt(car[c]);
        x2[i] = v;
        p += v * sac[c];
    }
    red[tid] = p; __syncthreads();
    for (int s = 64; s > 0; s >>= 1){ if (tid < s) red[tid] += red[tid + s]; __syncthreads(); }
    const float sa = sigmoid_f(red[0] + sab[0]);
    __syncthreads();
    float q = 0.f;
    #pragma unroll
    for (int i = 0; i < 3; ++i){
        const int c = tid + i * 128;
        x2[i] *= sa;
        q += x2[i] * decw[c];
    }
    red[tid] = q; __syncthreads();
    for (int s = 64; s > 0; s >>= 1){ if (tid < s) red[tid] += red[tid + s]; __syncthreads(); }
    const float xg = gelu_f(red[0] + decb[0]);
    #pragma unroll
    for (int i = 0; i < 3; ++i){
        const int c = tid + i * 128;
        const float sg = sigma[c];
        stv(&xr[c], x2[i] + sg * (x2[i] - xg));
    }
}

// Row softmax over N columns, in place (bf16), N/256 <= 16
__global__ __launch_bounds__(256) void softmax_rows_k(bf16* __restrict__ S, int N)
{
    __shared__ float red[256];
    const int row = blockIdx.x;
    bf16* r = S + (size_t)row * N;
    const int tid = threadIdx.x;
    float m = -3.4e38f;
    for (int i = tid; i < N; i += 256) m = fmaxf(m, cvt(r[i]));
    red[tid] = m; __syncthreads();
    for (int s = 128; s > 0; s >>= 1){ if (tid < s) red[tid] = fmaxf(red[tid], red[tid + s]); __syncthreads(); }
    m = red[0]; __syncthreads();
    float sum = 0.f;
    float ev[16];
    int c = 0;
    for (int i = tid; i < N; i += 256){ const float e = expf(cvt(r[i]) - m); ev[c++] = e; sum += e; }
    red[tid] = sum; __syncthreads();
    for (int s = 128; s > 0; s >>= 1){ if (tid < s) red[tid] += red[tid + s]; __syncthreads(); }
    const float inv = 1.0f / red[0];
    c = 0;
    for (int i = tid; i < N; i += 256) stv(&r[i], ev[c++] * inv);
}

// acc (+)= sigmoid(gate) * a * scale[col]   (double sigmoid per ref)
__global__ __launch_bounds__(256) void combine_k(
    bf16* __restrict__ acc, const bf16* __restrict__ gate,
    const bf16* __restrict__ a, const float* __restrict__ scale, int init)
{
    const size_t idx = (size_t)blockIdx.x * 256 + threadIdx.x;
    if (idx >= (size_t)NB * DM) return;
    const int col = (int)(idx % DM);
    const float v = sigmoid_f(cvt(gate[idx])) * cvt(a[idx]) * scale[col];
    stv(&acc[idx], init ? v : cvt(acc[idx]) + v);
}

// logits = acc @ cls_w.T + cls_b (768 -> 3), softmax(3), fp32 out. One wave per row.
__global__ __launch_bounds__(64) void cls_softmax_k(
    const bf16* __restrict__ acc, const float* __restrict__ w,
    const float* __restrict__ bias, float* __restrict__ out)
{
    const int b = blockIdx.x;
    const bf16* r = acc + (size_t)b * DM;
    float p0 = 0.f, p1 = 0.f, p2 = 0.f;
    for (int k = threadIdx.x; k < DM; k += 64){
        const float v = cvt(r[k]);
        p0 = fmaf(v, w[k],        p0);
        p1 = fmaf(v, w[DM + k],   p1);
        p2 = fmaf(v, w[2*DM + k], p2);
    }
    #pragma unroll
    for (int off = 32; off > 0; off >>= 1){
        p0 += __shfl_down(p0, off, 64);
        p1 += __shfl_down(p1, off, 64);
        p2 += __shfl_down(p2, off, 64);
    }
    if (threadIdx.x == 0){
        const float l0 = p0 + bias[0];
        const float l1 = p1 + bias[1];
        const float l2 = p2 + bias[2];
        const float mx = fmaxf(l0, fmaxf(l1, l2));
        const float e0 = expf(l0 - mx), e1 = expf(l1 - mx), e2 = expf(l2 - mx);
        const float inv = 1.f / (e0 + e1 + e2);
        out[(size_t)b * 3 + 0] = e0 * inv;
        out[(size_t)b * 3 + 1] = e1 * inv;
        out[(size_t)b * 3 + 2] = e2 * inv;
    }
}

extern "C" void kernel_launch(void* const* d_in, const int* in_sizes, int n_in,
                              void* d_out, int out_size, void* d_ws, size_t ws_size,
                              hipStream_t stream)
{
    const float* text   = (const float*)d_in[0];
    const float* image  = (const float*)d_in[1];
    const float* tl_w   = (const float*)d_in[2];
    const float* tl_b   = (const float*)d_in[3];
    const float* il_w   = (const float*)d_in[4];
    const float* il_b   = (const float*)d_in[5];
    // d_in[6..9] dead (seq_len=1 softmax == 1)
    const float* sda_wv = (const float*)d_in[10];
    const float* sda_bv = (const float*)d_in[11];
    const float* sda_wo = (const float*)d_in[12];
    const float* sda_bo = (const float*)d_in[13];
    const float* fda_w1 = (const float*)d_in[14];
    const float* fda_b1 = (const float*)d_in[15];
    const float* bn1_g  = (const float*)d_in[16];
    const float* bn1_b  = (const float*)d_in[17];
    const float* ca_w1  = (const float*)d_in[18];
    const float* ca_w2  = (const float*)d_in[19];
    const float* sa_w   = (const float*)d_in[20];
    const float* sa_b   = (const float*)d_in[21];
    const float* dec_w  = (const float*)d_in[22];
    const float* dec_b  = (const float*)d_in[23];
    const float* sigma  = (const float*)d_in[24];
    const float* fda_wf = (const float*)d_in[25];
    const float* fda_bf = (const float*)d_in[26];
    const float* bn2_g  = (const float*)d_in[27];
    const float* bn2_b  = (const float*)d_in[28];
    const float* dmi_wq = (const float*)d_in[29];
    const float* dmi_bq = (const float*)d_in[30];
    const float* dmi_wk = (const float*)d_in[31];
    const float* dmi_bk = (const float*)d_in[32];
    const float* dmi_wv = (const float*)d_in[33];
    const float* dmi_bv = (const float*)d_in[34];
    const float* tg_w1  = (const float*)d_in[35];
    const float* tg_b1  = (const float*)d_in[36];
    const float* tg_w2  = (const float*)d_in[37];
    const float* tg_b2  = (const float*)d_in[38];
    const float* ig_w1  = (const float*)d_in[39];
    const float* ig_b1  = (const float*)d_in[40];
    const float* ig_w2  = (const float*)d_in[41];
    const float* ig_b2  = (const float*)d_in[42];
    const float* t_scale= (const float*)d_in[43];
    const float* i_scale= (const float*)d_in[44];
    const float* cls_w  = (const float*)d_in[45];
    const float* cls_b  = (const float*)d_in[46];
    float* out = (float*)d_out;

    // ---- workspace layout (~71 MB; R3 used ~60 MB) ----
    char* base = (char*)d_ws;
    auto alloc = [&](size_t bytes){ void* p = (void*)base; base += (bytes + 255) & ~(size_t)255; return p; };
    const size_t SLOT = (size_t)NB * DM;                    // 3,145,728 elements
    const size_t W768 = (size_t)768 * 768;
    bf16* tl_wb   = (bf16*)alloc(W768 * 2);
    bf16* il_wb   = (bf16*)alloc(W768 * 2);
    bf16* sda_wvb = (bf16*)alloc((size_t)512 * 768 * 2);
    bf16* sda_wob = (bf16*)alloc((size_t)768 * 512 * 2);
    bf16* fda_wfb = (bf16*)alloc((size_t)768 * 384 * 2);
    bf16* dmi_wqb = (bf16*)alloc(W768 * 2);
    bf16* dmi_wkb = (bf16*)alloc(W768 * 2);
    bf16* dmi_wvb = (bf16*)alloc(W768 * 2);
    bf16* tg_w1b  = (bf16*)alloc(W768 * 2);
    bf16* tg_w2b  = (bf16*)alloc(W768 * 2);
    bf16* ig_w1b  = (bf16*)alloc(W768 * 2);
    bf16* ig_w2b  = (bf16*)alloc(W768 * 2);
    bf16* w1c     = (bf16*)alloc((size_t)384 * 768 * 2);
    float* sac    = (float*)alloc(1536 * 4);
    bf16* B0 = (bf16*)alloc(SLOT * 2);
    bf16* B1 = (bf16*)alloc(SLOT * 2);
    bf16* B2 = (bf16*)alloc(SLOT * 2);
    bf16* B3 = (bf16*)alloc(SLOT * 2);
    bf16* B4 = (bf16*)alloc(SLOT * 2);   // also: Xt at start, V^T during dmi
    bf16* B5 = (bf16*)alloc(SLOT * 2);   // also: Xi at start, a during dmi
    bf16* B6 = (bf16*)alloc(SLOT * 2);   // gated-output accumulator
    bf16* SCc = (bf16*)alloc((size_t)CH * NB * 2);          // 16 MB score chunk

    const float bnscale = 1.0f / sqrtf(1.0f + 1e-5f);
    const float iscale  = 1.0f / sqrtf(768.0f);
    const dim3 blk(256);
    auto gridm = [](int M, int N){ return dim3(N / 128, M / 128); };
    auto gridv = [](int M, int N){ return dim3((N + 63) / 64, (M + 63) / 64); };

    // batched fp32->bf16 conversion
    CvtDesc cd;
    const float* srcs[NCVT] = {text, image, tl_w, il_w, sda_wv, sda_wo, fda_wf,
                               dmi_wq, dmi_wk, dmi_wv, tg_w1, tg_w2, ig_w1, ig_w2};
    bf16* dsts[NCVT] = {B4, B5, tl_wb, il_wb, sda_wvb, sda_wob, fda_wfb,
                        dmi_wqb, dmi_wkb, dmi_wvb, tg_w1b, tg_w2b, ig_w1b, ig_w2b};
    int   lens[NCVT] = {(int)SLOT, (int)SLOT, (int)W768, (int)W768, 512*768, 768*512, 768*384,
                        (int)W768, (int)W768, (int)W768, (int)W768, (int)W768, (int)W768, (int)W768};
    for (int i = 0; i < NCVT; ++i){ cd.s[i] = srcs[i]; cd.d[i] = dsts[i]; cd.n[i] = lens[i]; }
    cvt_k<<<dim3((int)(SLOT / 1024), NCVT), blk, 0, stream>>>(cd);

    extract_k<<<dim3((384 * 768 + 255) / 256), blk, 0, stream>>>(fda_w1, sa_w, w1c, sac);

    // t0 = gelu(text @ tl_w^T + tl_b) -> B0 ; im0 -> B1   (Xt=B4, Xi=B5 die here)
    mgemm_k<bf16, 0><<<gridm(NB, DM), blk, 0, stream>>>(B4, tl_wb, B0, NB, DM, DM, tl_b, 1.f, nullptr, nullptr, 1);
    mgemm_k<bf16, 0><<<gridm(NB, DM), blk, 0, stream>>>(B5, il_wb, B1, NB, DM, DM, il_b, 1.f, nullptr, nullptr, 1);

    // degenerate self-attn: t1 = (t0 @ wv^T + bv) @ wo^T + bo -> B3
    mgemm_k<bf16, 0><<<gridm(NB, 512), blk, 0, stream>>>(B0, sda_wvb, B2, NB, 512, DM, sda_bv, 1.f, nullptr, nullptr, 0);
    mgemm_k<bf16, 0><<<gridm(NB, DM),  blk, 0, stream>>>(B2, sda_wob, B3, NB, DM, 512, sda_bo, 1.f, nullptr, nullptr, 0);

    // FDA: x1 = gelu((im0 @ w1c^T + b1)*bnscale*g1 + bb1) -> B0 (B,384)
    mgemm_k<bf16, 0><<<gridm(NB, 384), blk, 0, stream>>>(B1, w1c, B0, NB, 384, DM, fda_b1, bnscale, bn1_g, bn1_b, 1);
    // channel attention (tiny K/N=24): VALU path
    gemm_k<bf16, float, bf16><<<gridv(NB, 24),  blk, 0, stream>>>(B0, ca_w1, B2, NB, 24, 384, nullptr, 1.f, nullptr, nullptr, 1);
    gemm_k<bf16, float, bf16><<<gridv(NB, 384), blk, 0, stream>>>(B2, ca_w2, B4, NB, 384, 24, nullptr, 1.f, nullptr, nullptr, 2);
    fda_pointwise_k<<<dim3(NB), dim3(128), 0, stream>>>(B0, B4, sac, sa_b, dec_w, dec_b, sigma);
    // im1 = gelu((x4 @ wf^T + bf)*bnscale*g2 + bb2) -> B1
    mgemm_k<bf16, 0><<<gridm(NB, DM), blk, 0, stream>>>(B0, fda_wfb, B1, NB, DM, 384, fda_bf, bnscale, bn2_g, bn2_b, 1);

    for (int d = 0; d < 2; ++d){
        const bf16* qsrc = d == 0 ? B3 : B1;   // t1 : im1
        const bf16* kvsrc= d == 0 ? B1 : B3;   // im1 : t1
        const bf16* gw1b = d == 0 ? tg_w1b : ig_w1b;
        const float* gb1 = d == 0 ? tg_b1 : ig_b1;
        const bf16* gw2b = d == 0 ? tg_w2b : ig_w2b;
        const float* gb2 = d == 0 ? tg_b2 : ig_b2;
        const float* sc  = d == 0 ? t_scale : i_scale;
        // q -> B0, k -> B2, v^T -> B4 (transposed store: (DM, NB))
        mgemm_k<bf16, 0><<<gridm(NB, DM), blk, 0, stream>>>(qsrc,  dmi_wqb, B0, NB, DM, DM, dmi_bq, 1.f, nullptr, nullptr, 0);
        mgemm_k<bf16, 0><<<gridm(NB, DM), blk, 0, stream>>>(kvsrc, dmi_wkb, B2, NB, DM, DM, dmi_bk, 1.f, nullptr, nullptr, 0);
        mgemm_k<bf16, 1><<<gridm(NB, DM), blk, 0, stream>>>(kvsrc, dmi_wvb, B4, NB, DM, DM, dmi_bv, 1.f, nullptr, nullptr, 0);
        // attention in 2 row-chunks of CH: a -> B5
        for (int c = 0; c < NB / CH; ++c){
            const bf16* qc = B0 + (size_t)c * CH * DM;
            bf16*       ac = B5 + (size_t)c * CH * DM;
            mgemm_k<bf16, 0><<<gridm(CH, NB), blk, 0, stream>>>(qc, B2, SCc, CH, NB, DM, nullptr, iscale, nullptr, nullptr, 0);
            softmax_rows_k<<<dim3(CH), blk, 0, stream>>>(SCc, NB);
            mgemm_k<bf16, 0><<<gridm(CH, DM), blk, 0, stream>>>(SCc, B4, ac, CH, DM, NB, nullptr, 1.f, nullptr, nullptr, 0);
        }
        // gate = sigmoid(relu(a@gw1^T+gb1)@gw2^T+gb2)
        mgemm_k<bf16, 0><<<gridm(NB, DM), blk, 0, stream>>>(B5, gw1b, B0, NB, DM, DM, gb1, 1.f, nullptr, nullptr, 3);
        mgemm_k<bf16, 0><<<gridm(NB, DM), blk, 0, stream>>>(B0, gw2b, B2, NB, DM, DM, gb2, 1.f, nullptr, nullptr, 2);
        combine_k<<<dim3((NB * DM + 255) / 256), blk, 0, stream>>>(B6, B2, B5, sc, d == 0 ? 1 : 0);
    }

    cls_softmax_k<<<dim3(NB), dim3(64), 0, stream>>>(B6, cls_w, cls_b, out);
}

// Round 5
// 728.762 us; speedup vs baseline: 10.0591x; 1.6413x over previous
//
#include <hip/hip_runtime.h>
#include <hip/hip_bf16.h>
#include <math.h>

typedef __hip_bfloat16 bf16;
typedef __bf16 bf16x8 __attribute__((ext_vector_type(8)));
typedef float f32x4 __attribute__((ext_vector_type(4)));
typedef unsigned short u16;
typedef u16 u16x8 __attribute__((ext_vector_type(8)));

#define NB 4096          // batch rows
#define DM 768           // model dim
#define CH_FB 1024       // fallback attention row-chunk

__device__ __forceinline__ float cvt(float x){ return x; }
__device__ __forceinline__ float cvt(bf16 x){ return __bfloat162float(x); }
__device__ __forceinline__ void stv(float* p, float v){ *p = v; }
__device__ __forceinline__ void stv(bf16* p, float v){ *p = __float2bfloat16(v); }

__device__ __forceinline__ float gelu_f(float x){
    return 0.5f * x * (1.0f + erff(x * 0.70710678118654752440f));
}
__device__ __forceinline__ float sigmoid_f(float x){
    return 1.0f / (1.0f + expf(-x));
}

__device__ __forceinline__ void async_copy16(const void* g, void* l){
    __builtin_amdgcn_global_load_lds((const __attribute__((address_space(1))) void*)g,
                                     (__attribute__((address_space(3))) void*)l, 16, 0, 0);
}

// ---------------------------------------------------------------------------
// Multi-job MFMA GEMM: per z: C = act((A @ Bm^T + b0) * alpha * gv + b1)
// A: (M,K) bf16 row-major. Bm: (N,K) bf16 row-major. M%128==0, N%128==0, K%32==0.
// trans=1: store C^T into (N,M). LDS XOR-chunk swizzle kills 8-way conflicts.
// ---------------------------------------------------------------------------
#define MAXJ 6
struct Jobs {
    const bf16* A[MAXJ]; const bf16* B[MAXJ]; bf16* C[MAXJ];
    const float* b0[MAXJ]; const float* gv[MAXJ]; const float* b1[MAXJ];
    int act[MAXJ]; int trans[MAXJ];
};

__global__ __launch_bounds__(256) void mgemm_k(Jobs jb, int M, int N, int K, float alpha)
{
    const int z = blockIdx.z;
    const bf16* __restrict__ A  = jb.A[z];
    const bf16* __restrict__ Bm = jb.B[z];
    bf16* __restrict__ C        = jb.C[z];
    const float* __restrict__ bias0 = jb.b0[z];
    const float* __restrict__ gvec  = jb.gv[z];
    const float* __restrict__ bias1 = jb.b1[z];
    const int act = jb.act[z], trans = jb.trans[z];

    __shared__ __align__(16) bf16 Asl[128 * 32];
    __shared__ __align__(16) bf16 Bsl[128 * 32];
    const int tid  = threadIdx.x;
    const int wave = tid >> 6;
    const int lane = tid & 63;
    const int row0 = blockIdx.y * 128;
    const int col0 = blockIdx.x * 128;
    const int wrow = (wave & 1) * 64;
    const int wcol = (wave >> 1) * 64;
    const int fl   = lane & 15;
    // staging: lane covers (r = lane>>2, phys chunk = lane&3); source chunk XOR-swizzled
    const int srow = lane >> 2;
    const int scol = (((lane & 3) ^ ((lane >> 3) & 3))) * 8;
    // fragment read: logical chunk (lane>>4) lives at phys chunk ^ ((row>>1)&3); row = base16 + fl
    const int ko2  = (((lane >> 4) ^ ((fl >> 1) & 3))) * 8;

    const bf16* pA = A  + (size_t)(row0 + wave * 32 + srow) * K + scol;
    const bf16* pB = Bm + (size_t)(col0 + wave * 32 + srow) * K + scol;
    bf16* ldA = &Asl[(wave * 32) * 32];
    bf16* ldB = &Bsl[(wave * 32) * 32];
    const size_t rstep = (size_t)16 * K;

    f32x4 acc[4][4] = {};
    for (int k0 = 0; k0 < K; k0 += 32){
        async_copy16(pA,         ldA);
        async_copy16(pA + rstep, ldA + 16 * 32);
        async_copy16(pB,         ldB);
        async_copy16(pB + rstep, ldB + 16 * 32);
        pA += 32; pB += 32;
        __syncthreads();
        bf16x8 af[4], bfv[4];
        #pragma unroll
        for (int i = 0; i < 4; ++i){
            af[i]  = *(const bf16x8*)&Asl[(wrow + i * 16 + fl) * 32 + ko2];
            bfv[i] = *(const bf16x8*)&Bsl[(wcol + i * 16 + fl) * 32 + ko2];
        }
        #pragma unroll
        for (int mi = 0; mi < 4; ++mi)
            #pragma unroll
            for (int ni = 0; ni < 4; ++ni)
                acc[mi][ni] = __builtin_amdgcn_mfma_f32_16x16x32_bf16(af[mi], bfv[ni], acc[mi][ni], 0, 0, 0);
        __syncthreads();
    }

    // C/D layout: col = lane&15, row = (lane>>4)*4 + reg   (verified R4: absmax 0)
    #pragma unroll
    for (int ni = 0; ni < 4; ++ni){
        const int col = col0 + wcol + ni * 16 + fl;
        const float b0 = bias0 ? bias0[col] : 0.f;
        const float gm = (gvec ? gvec[col] : 1.f) * alpha;
        const float b1 = bias1 ? bias1[col] : 0.f;
        #pragma unroll
        for (int mi = 0; mi < 4; ++mi){
            const int rbase = row0 + wrow + mi * 16 + (lane >> 4) * 4;
            #pragma unroll
            for (int r = 0; r < 4; ++r){
                float v = (acc[mi][ni][r] + b0) * gm + b1;
                if      (act == 1) v = gelu_f(v);
                else if (act == 2) v = sigmoid_f(v);
                else if (act == 3) v = fmaxf(v, 0.f);
                if (trans) stv(&C[(size_t)col * M + rbase + r], v);
                else       stv(&C[(size_t)(rbase + r) * N + col], v);
            }
        }
    }
}

// VALU GEMM for tiny shapes (channel attention, N or K = 24)
template<typename TA, typename TB, typename TC>
__global__ __launch_bounds__(256) void gemm_k(
    const TA* __restrict__ A, const TB* __restrict__ Bm, TC* __restrict__ C,
    int M, int N, int K,
    const float* __restrict__ bias0, float alpha, const float* __restrict__ gvec,
    const float* __restrict__ bias1, int act)
{
    constexpr int LDT = 68;
    __shared__ float As[16 * LDT];
    __shared__ float Bs[16 * LDT];
    const int tid = threadIdx.x;
    const int tx  = tid & 15;
    const int ty  = tid >> 4;
    const int row0 = blockIdx.y * 64;
    const int col0 = blockIdx.x * 64;

    float acc[4][4] = {};
    const int nK = (K + 15) >> 4;
    for (int kt = 0; kt < nK; ++kt){
        const int k0 = kt << 4;
        {
            const int k  = tid & 15;
            const int kg = k0 + k;
            #pragma unroll
            for (int i = 0; i < 4; ++i){
                const int m  = (tid >> 4) + i * 16;
                const int mg = row0 + m;
                float v = 0.f;
                if (mg < M && kg < K) v = cvt(A[(size_t)mg * K + kg]);
                As[k * LDT + m] = v;
            }
        }
        {
            const int k  = tid & 15;
            const int kg = k0 + k;
            #pragma unroll
            for (int i = 0; i < 4; ++i){
                const int n  = (tid >> 4) + i * 16;
                const int ng = col0 + n;
                float v = 0.f;
                if (ng < N && kg < K) v = cvt(Bm[(size_t)ng * K + kg]);
                Bs[k * LDT + n] = v;
            }
        }
        __syncthreads();
        #pragma unroll
        for (int kk = 0; kk < 16; ++kk){
            const float4 av = *(const float4*)&As[kk * LDT + ty * 4];
            const float4 bv = *(const float4*)&Bs[kk * LDT + tx * 4];
            const float a4[4] = {av.x, av.y, av.z, av.w};
            const float b4[4] = {bv.x, bv.y, bv.z, bv.w};
            #pragma unroll
            for (int i = 0; i < 4; ++i)
                #pragma unroll
                for (int j = 0; j < 4; ++j)
                    acc[i][j] = fmaf(a4[i], b4[j], acc[i][j]);
        }
        __syncthreads();
    }
    #pragma unroll
    for (int j = 0; j < 4; ++j){
        const int cg = col0 + tx * 4 + j;
        if (cg >= N) continue;
        const float b0 = bias0 ? bias0[cg] : 0.f;
        const float gm = (gvec ? gvec[cg] : 1.f) * alpha;
        const float b1 = bias1 ? bias1[cg] : 0.f;
        #pragma unroll
        for (int i = 0; i < 4; ++i){
            const int rg = row0 + ty * 4 + i;
            if (rg >= M) continue;
            float v = (acc[i][j] + b0) * gm + b1;
            if      (act == 1) v = gelu_f(v);
            else if (act == 2) v = sigmoid_f(v);
            else if (act == 3) v = fmaxf(v, 0.f);
            stv(&C[(size_t)rg * N + cg], v);
        }
    }
}

// Batched fp32 -> bf16 conversion
#define NCVT 14
struct CvtDesc { const float* s[NCVT]; bf16* d[NCVT]; int n[NCVT]; };
__global__ __launch_bounds__(256) void cvt_k(CvtDesc cd)
{
    const int e = blockIdx.y;
    const int base = (blockIdx.x * 256 + threadIdx.x) * 4;
    if (base >= cd.n[e]) return;
    const float4 v = *(const float4*)(cd.s[e] + base);
    union { bf16 h[4]; unsigned long long u; } o;
    o.h[0] = __float2bfloat16(v.x);
    o.h[1] = __float2bfloat16(v.y);
    o.h[2] = __float2bfloat16(v.z);
    o.h[3] = __float2bfloat16(v.w);
    *(unsigned long long*)(cd.d[e] + base) = o.u;
}

__global__ __launch_bounds__(256) void extract_k(
    const float* __restrict__ w1, const float* __restrict__ saw,
    bf16* __restrict__ w1c, float* __restrict__ sac)
{
    const int idx = blockIdx.x * 256 + threadIdx.x;
    if (idx < 384 * 768){
        const int oc = idx / 768, ic = idx % 768;
        w1c[idx] = __float2bfloat16(w1[(size_t)oc * 6912 + (size_t)ic * 9 + 4]);
    }
    if (idx < 384) sac[idx] = saw[(size_t)idx * 49 + 24];
}

__global__ __launch_bounds__(128) void fda_pointwise_k(
    bf16* __restrict__ x, const bf16* __restrict__ ca,
    const float* __restrict__ sac, const float* __restrict__ sab,
    const float* __restrict__ decw, const float* __restrict__ decb,
    const float* __restrict__ sigma)
{
    __shared__ float red[128];
    const int b = blockIdx.x;
    const int tid = threadIdx.x;
    bf16* xr = x + (size_t)b * 384;
    const bf16* car = ca + (size_t)b * 384;
    float x2[3];
    float p = 0.f;
    #pragma unroll
    for (int i = 0; i < 3; ++i){
        const int c = tid + i * 128;
        const float v = cvt(xr[c]) * cvt(car[c]);
        x2[i] = v;
        p += v * sac[c];
    }
    red[tid] = p; __syncthreads();
    for (int s = 64; s > 0; s >>= 1){ if (tid < s) red[tid] += red[tid + s]; __syncthreads(); }
    const float sa = sigmoid_f(red[0] + sab[0]);
    __syncthreads();
    float q = 0.f;
    #pragma unroll
    for (int i = 0; i < 3; ++i){
        const int c = tid + i * 128;
        x2[i] *= sa;
        q += x2[i] * decw[c];
    }
    red[tid] = q; __syncthreads();
    for (int s = 64; s > 0; s >>= 1){ if (tid < s) red[tid] += red[tid + s]; __syncthreads(); }
    const float xg = gelu_f(red[0] + decb[0]);
    #pragma unroll
    for (int i = 0; i < 3; ++i){
        const int c = tid + i * 128;
        const float sg = sigma[c];
        stv(&xr[c], x2[i] + sg * (x2[i] - xg));
    }
}

// Row softmax: one block per 4096-wide row, coalesced 16-elem/thread
__global__ __launch_bounds__(256) void softmax_rows_k(bf16* __restrict__ S)
{
    __shared__ float red[256];
    const int tid = threadIdx.x;
    u16* r = (u16*)(S + (size_t)blockIdx.x * NB) + tid * 16;
    u16x8 h0 = *(const u16x8*)r;
    u16x8 h1 = *(const u16x8*)(r + 8);
    float v[16];
    #pragma unroll
    for (int i = 0; i < 8; ++i){
        v[i]     = __uint_as_float((unsigned)h0[i] << 16);
        v[8 + i] = __uint_as_float((unsigned)h1[i] << 16);
    }
    float m = v[0];
    #pragma unroll
    for (int i = 1; i < 16; ++i) m = fmaxf(m, v[i]);
    red[tid] = m; __syncthreads();
    for (int s = 128; s > 0; s >>= 1){ if (tid < s) red[tid] = fmaxf(red[tid], red[tid + s]); __syncthreads(); }
    m = red[0]; __syncthreads();
    float sum = 0.f;
    #pragma unroll
    for (int i = 0; i < 16; ++i){ v[i] = expf(v[i] - m); sum += v[i]; }
    red[tid] = sum; __syncthreads();
    for (int s = 128; s > 0; s >>= 1){ if (tid < s) red[tid] += red[tid + s]; __syncthreads(); }
    const float inv = 1.0f / red[0];
    union { u16x8 h; } o0, o1;
    #pragma unroll
    for (int i = 0; i < 8; ++i){
        o0.h[i] = __bfloat16_as_ushort(__float2bfloat16(v[i] * inv));
        o1.h[i] = __bfloat16_as_ushort(__float2bfloat16(v[8 + i] * inv));
    }
    *(u16x8*)r = o0.h;
    *(u16x8*)(r + 8) = o1.h;
}

// acc = sig(g1)*a1*s1 + sig(g2)*a2*s2  (both dmi terms fused)
__global__ __launch_bounds__(256) void combine2_k(
    bf16* __restrict__ acc,
    const bf16* __restrict__ g1, const bf16* __restrict__ a1, const float* __restrict__ s1,
    const bf16* __restrict__ g2, const bf16* __restrict__ a2, const float* __restrict__ s2)
{
    const size_t idx = (size_t)blockIdx.x * 256 + threadIdx.x;
    if (idx >= (size_t)NB * DM) return;
    const int col = (int)(idx % DM);
    const float v = sigmoid_f(cvt(g1[idx])) * cvt(a1[idx]) * s1[col]
                  + sigmoid_f(cvt(g2[idx])) * cvt(a2[idx]) * s2[col];
    stv(&acc[idx], v);
}

// fallback single-term combine
__global__ __launch_bounds__(256) void combine_k(
    bf16* __restrict__ acc, const bf16* __restrict__ gate,
    const bf16* __restrict__ a, const float* __restrict__ scale, int init)
{
    const size_t idx = (size_t)blockIdx.x * 256 + threadIdx.x;
    if (idx >= (size_t)NB * DM) return;
    const int col = (int)(idx % DM);
    const float v = sigmoid_f(cvt(gate[idx])) * cvt(a[idx]) * scale[col];
    stv(&acc[idx], init ? v : cvt(acc[idx]) + v);
}

__global__ __launch_bounds__(64) void cls_softmax_k(
    const bf16* __restrict__ acc, const float* __restrict__ w,
    const float* __restrict__ bias, float* __restrict__ out)
{
    const int b = blockIdx.x;
    const bf16* r = acc + (size_t)b * DM;
    float p0 = 0.f, p1 = 0.f, p2 = 0.f;
    for (int k = threadIdx.x; k < DM; k += 64){
        const float v = cvt(r[k]);
        p0 = fmaf(v, w[k],        p0);
        p1 = fmaf(v, w[DM + k],   p1);
        p2 = fmaf(v, w[2*DM + k], p2);
    }
    #pragma unroll
    for (int off = 32; off > 0; off >>= 1){
        p0 += __shfl_down(p0, off, 64);
        p1 += __shfl_down(p1, off, 64);
        p2 += __shfl_down(p2, off, 64);
    }
    if (threadIdx.x == 0){
        const float l0 = p0 + bias[0];
        const float l1 = p1 + bias[1];
        const float l2 = p2 + bias[2];
        const float mx = fmaxf(l0, fmaxf(l1, l2));
        const float e0 = expf(l0 - mx), e1 = expf(l1 - mx), e2 = expf(l2 - mx);
        const float inv = 1.f / (e0 + e1 + e2);
        out[(size_t)b * 3 + 0] = e0 * inv;
        out[(size_t)b * 3 + 1] = e1 * inv;
        out[(size_t)b * 3 + 2] = e2 * inv;
    }
}

extern "C" void kernel_launch(void* const* d_in, const int* in_sizes, int n_in,
                              void* d_out, int out_size, void* d_ws, size_t ws_size,
                              hipStream_t stream)
{
    const float* text   = (const float*)d_in[0];
    const float* image  = (const float*)d_in[1];
    const float* tl_w   = (const float*)d_in[2];
    const float* tl_b   = (const float*)d_in[3];
    const float* il_w   = (const float*)d_in[4];
    const float* il_b   = (const float*)d_in[5];
    const float* sda_wv = (const float*)d_in[10];
    const float* sda_bv = (const float*)d_in[11];
    const float* sda_wo = (const float*)d_in[12];
    const float* sda_bo = (const float*)d_in[13];
    const float* fda_w1 = (const float*)d_in[14];
    const float* fda_b1 = (const float*)d_in[15];
    const float* bn1_g  = (const float*)d_in[16];
    const float* bn1_b  = (const float*)d_in[17];
    const float* ca_w1  = (const float*)d_in[18];
    const float* ca_w2  = (const float*)d_in[19];
    const float* sa_w   = (const float*)d_in[20];
    const float* sa_b   = (const float*)d_in[21];
    const float* dec_w  = (const float*)d_in[22];
    const float* dec_b  = (const float*)d_in[23];
    const float* sigma  = (const float*)d_in[24];
    const float* fda_wf = (const float*)d_in[25];
    const float* fda_bf = (const float*)d_in[26];
    const float* bn2_g  = (const float*)d_in[27];
    const float* bn2_b  = (const float*)d_in[28];
    const float* dmi_wq = (const float*)d_in[29];
    const float* dmi_bq = (const float*)d_in[30];
    const float* dmi_wk = (const float*)d_in[31];
    const float* dmi_bk = (const float*)d_in[32];
    const float* dmi_wv = (const float*)d_in[33];
    const float* dmi_bv = (const float*)d_in[34];
    const float* tg_w1  = (const float*)d_in[35];
    const float* tg_b1  = (const float*)d_in[36];
    const float* tg_w2  = (const float*)d_in[37];
    const float* tg_b2  = (const float*)d_in[38];
    const float* ig_w1  = (const float*)d_in[39];
    const float* ig_b1  = (const float*)d_in[40];
    const float* ig_w2  = (const float*)d_in[41];
    const float* ig_b2  = (const float*)d_in[42];
    const float* t_scale= (const float*)d_in[43];
    const float* i_scale= (const float*)d_in[44];
    const float* cls_w  = (const float*)d_in[45];
    const float* cls_b  = (const float*)d_in[46];
    float* out = (float*)d_out;

    // ---- workspace ----
    char* base = (char*)d_ws;
    auto alloc = [&](size_t bytes){ void* p = (void*)base; base += (bytes + 255) & ~(size_t)255; return p; };
    const size_t SLOT = (size_t)NB * DM;
    const size_t W768 = (size_t)768 * 768;
    bf16* tl_wb   = (bf16*)alloc(W768 * 2);
    bf16* il_wb   = (bf16*)alloc(W768 * 2);
    bf16* sda_wvb = (bf16*)alloc((size_t)512 * 768 * 2);
    bf16* sda_wob = (bf16*)alloc((size_t)768 * 512 * 2);
    bf16* fda_wfb = (bf16*)alloc((size_t)768 * 384 * 2);
    bf16* dmi_wqb = (bf16*)alloc(W768 * 2);
    bf16* dmi_wkb = (bf16*)alloc(W768 * 2);
    bf16* dmi_wvb = (bf16*)alloc(W768 * 2);
    bf16* tg_w1b  = (bf16*)alloc(W768 * 2);
    bf16* tg_w2b  = (bf16*)alloc(W768 * 2);
    bf16* ig_w1b  = (bf16*)alloc(W768 * 2);
    bf16* ig_w2b  = (bf16*)alloc(W768 * 2);
    bf16* w1c     = (bf16*)alloc((size_t)384 * 768 * 2);
    float* sac    = (float*)alloc(1536 * 4);
    bf16* SL[8];
    for (int i = 0; i < 8; ++i) SL[i] = (bf16*)alloc(SLOT * 2);
    const size_t used = (size_t)(base - (char*)d_ws);
    const bool full = ws_size >= used + 2ull * NB * NB * 2;   // two 32 MB score mats
    bf16* SC1 = (bf16*)alloc(full ? (size_t)NB * NB * 2 : (size_t)CH_FB * NB * 2);
    bf16* SC2 = full ? (bf16*)alloc((size_t)NB * NB * 2) : SC1;

    const float bnscale = 1.0f / sqrtf(1.0f + 1e-5f);
    const float iscale  = 1.0f / sqrtf(768.0f);
    const dim3 blk(256);
    auto gridv = [](int M, int N){ return dim3((N + 63) / 64, (M + 63) / 64); };

    // single-job helper
    auto g1 = [&](const bf16* A, const bf16* B, bf16* C, int M, int N, int K,
                  const float* b0, float al, const float* gv, const float* b1, int act, int trans){
        Jobs jb{};
        jb.A[0]=A; jb.B[0]=B; jb.C[0]=C; jb.b0[0]=b0; jb.gv[0]=gv; jb.b1[0]=b1;
        jb.act[0]=act; jb.trans[0]=trans;
        mgemm_k<<<dim3(N/128, M/128, 1), blk, 0, stream>>>(jb, M, N, K, al);
    };

    // fp32 -> bf16 staging
    CvtDesc cd;
    const float* srcs[NCVT] = {text, image, tl_w, il_w, sda_wv, sda_wo, fda_wf,
                               dmi_wq, dmi_wk, dmi_wv, tg_w1, tg_w2, ig_w1, ig_w2};
    bf16* dsts[NCVT] = {SL[0], SL[1], tl_wb, il_wb, sda_wvb, sda_wob, fda_wfb,
                        dmi_wqb, dmi_wkb, dmi_wvb, tg_w1b, tg_w2b, ig_w1b, ig_w2b};
    int   lens[NCVT] = {(int)SLOT, (int)SLOT, (int)W768, (int)W768, 512*768, 768*512, 768*384,
                        (int)W768, (int)W768, (int)W768, (int)W768, (int)W768, (int)W768, (int)W768};
    for (int i = 0; i < NCVT; ++i){ cd.s[i] = srcs[i]; cd.d[i] = dsts[i]; cd.n[i] = lens[i]; }
    cvt_k<<<dim3((int)(SLOT / 1024), NCVT), blk, 0, stream>>>(cd);
    extract_k<<<dim3((384 * 768 + 255) / 256), blk, 0, stream>>>(fda_w1, sa_w, w1c, sac);

    // t0 -> SL2, im0 -> SL3 (z=2)
    {
        Jobs jb{};
        jb.A[0]=SL[0]; jb.B[0]=tl_wb; jb.C[0]=SL[2]; jb.b0[0]=tl_b; jb.act[0]=1;
        jb.A[1]=SL[1]; jb.B[1]=il_wb; jb.C[1]=SL[3]; jb.b0[1]=il_b; jb.act[1]=1;
        mgemm_k<<<dim3(DM/128, NB/128, 2), blk, 0, stream>>>(jb, NB, DM, DM, 1.f);
    }
    // degenerate self-attn: t1 -> SL4
    g1(SL[2], sda_wvb, SL[0], NB, 512, DM, sda_bv, 1.f, nullptr, nullptr, 0, 0);
    g1(SL[0], sda_wob, SL[4], NB, DM, 512, sda_bo, 1.f, nullptr, nullptr, 0, 0);
    // FDA -> im1 in SL5
    g1(SL[3], w1c, SL[0], NB, 384, DM, fda_b1, bnscale, bn1_g, bn1_b, 1, 0);
    gemm_k<bf16, float, bf16><<<gridv(NB, 24),  blk, 0, stream>>>(SL[0], ca_w1, SL[1], NB, 24, 384, nullptr, 1.f, nullptr, nullptr, 1);
    gemm_k<bf16, float, bf16><<<gridv(NB, 384), blk, 0, stream>>>(SL[1], ca_w2, SL[2], NB, 384, 24, nullptr, 1.f, nullptr, nullptr, 2);
    fda_pointwise_k<<<dim3(NB), dim3(128), 0, stream>>>(SL[0], SL[2], sac, sa_b, dec_w, dec_b, sigma);
    g1(SL[0], fda_wfb, SL[5], NB, DM, 384, fda_bf, bnscale, bn2_g, bn2_b, 1, 0);

    if (full){
        // QKV for both dmi (z=6): Q1->SL0 K1->SL1 V1t->SL2 Q2->SL3 K2->SL6 V2t->SL7
        {
            Jobs jb{};
            const bf16* As[6]  = {SL[4], SL[5], SL[5], SL[5], SL[4], SL[4]};
            const bf16* Bs[6]  = {dmi_wqb, dmi_wkb, dmi_wvb, dmi_wqb, dmi_wkb, dmi_wvb};
            bf16* Cs[6]        = {SL[0], SL[1], SL[2], SL[3], SL[6], SL[7]};
            const float* bs[6] = {dmi_bq, dmi_bk, dmi_bv, dmi_bq, dmi_bk, dmi_bv};
            const int tr[6]    = {0, 0, 1, 0, 0, 1};
            for (int i = 0; i < 6; ++i){ jb.A[i]=As[i]; jb.B[i]=Bs[i]; jb.C[i]=Cs[i]; jb.b0[i]=bs[i]; jb.trans[i]=tr[i]; }
            mgemm_k<<<dim3(DM/128, NB/128, 6), blk, 0, stream>>>(jb, NB, DM, DM, 1.f);
        }
        // scores (z=2, 2048 blocks)
        {
            Jobs jb{};
            jb.A[0]=SL[0]; jb.B[0]=SL[1]; jb.C[0]=SC1;
            jb.A[1]=SL[3]; jb.B[1]=SL[6]; jb.C[1]=SC2;
            mgemm_k<<<dim3(NB/128, NB/128, 2), blk, 0, stream>>>(jb, NB, NB, DM, iscale);
        }
        softmax_rows_k<<<dim3(2 * NB), blk, 0, stream>>>(SC1);   // SC2 contiguous after SC1
        // PV (z=2): a1 -> SL4, a2 -> SL5
        {
            Jobs jb{};
            jb.A[0]=SC1; jb.B[0]=SL[2]; jb.C[0]=SL[4];
            jb.A[1]=SC2; jb.B[1]=SL[7]; jb.C[1]=SL[5];
            mgemm_k<<<dim3(DM/128, NB/128, 2), blk, 0, stream>>>(jb, NB, DM, NB, 1.f);
        }
        // gates
        {
            Jobs jb{};
            jb.A[0]=SL[4]; jb.B[0]=tg_w1b; jb.C[0]=SL[0]; jb.b0[0]=tg_b1; jb.act[0]=3;
            jb.A[1]=SL[5]; jb.B[1]=ig_w1b; jb.C[1]=SL[1]; jb.b0[1]=ig_b1; jb.act[1]=3;
            mgemm_k<<<dim3(DM/128, NB/128, 2), blk, 0, stream>>>(jb, NB, DM, DM, 1.f);
        }
        {
            Jobs jb{};
            jb.A[0]=SL[0]; jb.B[0]=tg_w2b; jb.C[0]=SL[3]; jb.b0[0]=tg_b2; jb.act[0]=2;
            jb.A[1]=SL[1]; jb.B[1]=ig_w2b; jb.C[1]=SL[6]; jb.b0[1]=ig_b2; jb.act[1]=2;
            mgemm_k<<<dim3(DM/128, NB/128, 2), blk, 0, stream>>>(jb, NB, DM, DM, 1.f);
        }
        combine2_k<<<dim3((NB * DM + 255) / 256), blk, 0, stream>>>(SL[2], SL[3], SL[4], t_scale, SL[6], SL[5], i_scale);
        cls_softmax_k<<<dim3(NB), dim3(64), 0, stream>>>(SL[2], cls_w, cls_b, out);
    } else {
        // fallback: sequential dmi, chunked scores (proven-size workspace)
        for (int d = 0; d < 2; ++d){
            const bf16* qsrc = d == 0 ? SL[4] : SL[5];
            const bf16* kvsrc= d == 0 ? SL[5] : SL[4];
            Jobs jb{};
            const bf16* Bs[3]  = {dmi_wqb, dmi_wkb, dmi_wvb};
            const float* bs[3] = {dmi_bq, dmi_bk, dmi_bv};
            for (int i = 0; i < 3; ++i){
                jb.A[i] = i == 0 ? qsrc : kvsrc; jb.B[i]=Bs[i]; jb.C[i]=SL[i]; jb.b0[i]=bs[i]; jb.trans[i]= (i==2);
            }
            mgemm_k<<<dim3(DM/128, NB/128, 3), blk, 0, stream>>>(jb, NB, DM, DM, 1.f);
            for (int c = 0; c < NB / CH_FB; ++c){
                g1(SL[0] + (size_t)c * CH_FB * DM, SL[1], SC1, CH_FB, NB, DM, nullptr, iscale, nullptr, nullptr, 0, 0);
                softmax_rows_k<<<dim3(CH_FB), blk, 0, stream>>>(SC1);
                g1(SC1, SL[2], SL[3] + (size_t)c * CH_FB * DM, CH_FB, DM, NB, nullptr, 1.f, nullptr, nullptr, 0, 0);
            }
            const bf16* gw1b = d == 0 ? tg_w1b : ig_w1b;
            const float* gb1 = d == 0 ? tg_b1 : ig_b1;
            const bf16* gw2b = d == 0 ? tg_w2b : ig_w2b;
            const float* gb2 = d == 0 ? tg_b2 : ig_b2;
            const float* sc  = d == 0 ? t_scale : i_scale;
            g1(SL[3], gw1b, SL[0], NB, DM, DM, gb1, 1.f, nullptr, nullptr, 3, 0);
            g1(SL[0], gw2b, SL[1], NB, DM, DM, gb2, 1.f, nullptr, nullptr, 2, 0);
            combine_k<<<dim3((NB * DM + 255) / 256), blk, 0, stream>>>(SL[6], SL[1], SL[3], sc, d == 0 ? 1 : 0);
        }
        cls_softmax_k<<<dim3(NB), dim3(64), 0, stream>>>(SL[6], cls_w, cls_b, out);
    }
}

// Round 6
// 657.392 us; speedup vs baseline: 11.1512x; 1.1086x over previous
//
#include <hip/hip_runtime.h>
#include <hip/hip_bf16.h>
#include <math.h>

typedef __hip_bfloat16 bf16;
typedef __bf16 bf16x8 __attribute__((ext_vector_type(8)));
typedef float f32x4 __attribute__((ext_vector_type(4)));
typedef unsigned short u16;
typedef u16 u16x8 __attribute__((ext_vector_type(8)));

#define NB 4096          // batch rows
#define DM 768           // model dim

__device__ __forceinline__ float cvt(float x){ return x; }
__device__ __forceinline__ float cvt(bf16 x){ return __bfloat162float(x); }
__device__ __forceinline__ void stv(float* p, float v){ *p = v; }
__device__ __forceinline__ void stv(bf16* p, float v){ *p = __float2bfloat16(v); }

__device__ __forceinline__ float gelu_f(float x){
    return 0.5f * x * (1.0f + erff(x * 0.70710678118654752440f));
}
__device__ __forceinline__ float sigmoid_f(float x){
    return 1.0f / (1.0f + expf(-x));
}

__device__ __forceinline__ void async_copy16(const void* g, void* l){
    __builtin_amdgcn_global_load_lds((const __attribute__((address_space(1))) void*)g,
                                     (__attribute__((address_space(3))) void*)l, 16, 0, 0);
}

// ---------------------------------------------------------------------------
// Flat multi-job MFMA GEMM. Per job: C = act((A @ Bm^T + b0) * alpha * gv + b1)
// A: (M,ldA) bf16, uses cols [0,K). Bm: (N,ldB) bf16 (B^T layout), cols [0,K).
// M%128==0, N%128==0, K%32==0. trans=1: store C^T into (N,M).
// 1D grid; job located via blk0 table. XOR-chunk LDS swizzle (R5: 0 conflicts).
// ---------------------------------------------------------------------------
#define MAXJ 8
struct Job {
    const bf16* A; const bf16* B; bf16* C;
    const float* b0; const float* gv; const float* b1;
    int M, N, K, ldA, ldB, act, trans, blk0, nx;
    float alpha;
};
struct Jobs { Job j[MAXJ]; int nj; };

__global__ __launch_bounds__(256) void mgemm_k(Jobs jb)
{
    int z = 0;
    #pragma unroll
    for (int i = 1; i < MAXJ; ++i)
        if (i < jb.nj && (int)blockIdx.x >= jb.j[i].blk0) z = i;
    const Job& J = jb.j[z];
    const bf16* __restrict__ A  = J.A;
    const bf16* __restrict__ Bm = J.B;
    bf16* __restrict__ C        = J.C;
    const int bx = (int)blockIdx.x - J.blk0;
    const int gx = bx % J.nx;
    const int gy = bx / J.nx;
    const int M = J.M, N = J.N, K = J.K, ldA = J.ldA, ldB = J.ldB;

    __shared__ __align__(16) bf16 Asl[128 * 32];
    __shared__ __align__(16) bf16 Bsl[128 * 32];
    const int tid  = threadIdx.x;
    const int wave = tid >> 6;
    const int lane = tid & 63;
    const int row0 = gy * 128;
    const int col0 = gx * 128;
    const int wrow = (wave & 1) * 64;
    const int wcol = (wave >> 1) * 64;
    const int fl   = lane & 15;
    const int srow = lane >> 2;
    const int scol = (((lane & 3) ^ ((lane >> 3) & 3))) * 8;
    const int ko2  = (((lane >> 4) ^ ((fl >> 1) & 3))) * 8;

    const bf16* pA = A  + (size_t)(row0 + wave * 32 + srow) * ldA + scol;
    const bf16* pB = Bm + (size_t)(col0 + wave * 32 + srow) * ldB + scol;
    bf16* ldsA = &Asl[(wave * 32) * 32];
    bf16* ldsB = &Bsl[(wave * 32) * 32];
    const size_t rstepA = (size_t)16 * ldA;
    const size_t rstepB = (size_t)16 * ldB;

    f32x4 acc[4][4] = {};
    for (int k0 = 0; k0 < K; k0 += 32){
        async_copy16(pA,          ldsA);
        async_copy16(pA + rstepA, ldsA + 16 * 32);
        async_copy16(pB,          ldsB);
        async_copy16(pB + rstepB, ldsB + 16 * 32);
        pA += 32; pB += 32;
        __syncthreads();
        bf16x8 af[4], bfv[4];
        #pragma unroll
        for (int i = 0; i < 4; ++i){
            af[i]  = *(const bf16x8*)&Asl[(wrow + i * 16 + fl) * 32 + ko2];
            bfv[i] = *(const bf16x8*)&Bsl[(wcol + i * 16 + fl) * 32 + ko2];
        }
        #pragma unroll
        for (int mi = 0; mi < 4; ++mi)
            #pragma unroll
            for (int ni = 0; ni < 4; ++ni)
                acc[mi][ni] = __builtin_amdgcn_mfma_f32_16x16x32_bf16(af[mi], bfv[ni], acc[mi][ni], 0, 0, 0);
        __syncthreads();
    }

    // C/D layout: col = lane&15, row = (lane>>4)*4 + reg  (verified R4/R5: absmax 0)
    #pragma unroll
    for (int ni = 0; ni < 4; ++ni){
        const int col = col0 + wcol + ni * 16 + fl;
        const float b0 = J.b0 ? J.b0[col] : 0.f;
        const float gm = (J.gv ? J.gv[col] : 1.f) * J.alpha;
        const float b1 = J.b1 ? J.b1[col] : 0.f;
        #pragma unroll
        for (int mi = 0; mi < 4; ++mi){
            const int rbase = row0 + wrow + mi * 16 + (lane >> 4) * 4;
            #pragma unroll
            for (int r = 0; r < 4; ++r){
                float v = (acc[mi][ni][r] + b0) * gm + b1;
                if      (J.act == 1) v = gelu_f(v);
                else if (J.act == 2) v = sigmoid_f(v);
                else if (J.act == 3) v = fmaxf(v, 0.f);
                if (J.trans) stv(&C[(size_t)col * M + rbase + r], v);
                else         stv(&C[(size_t)(rbase + r) * N + col], v);
            }
        }
    }
}

// Batched fp32 -> bf16 conversion
#define NCVT 14
struct CvtDesc { const float* s[NCVT]; bf16* d[NCVT]; int n[NCVT]; };
__global__ __launch_bounds__(256) void cvt_k(CvtDesc cd)
{
    const int e = blockIdx.y;
    const int base = (blockIdx.x * 256 + threadIdx.x) * 4;
    if (base >= cd.n[e]) return;
    const float4 v = *(const float4*)(cd.s[e] + base);
    union { bf16 h[4]; unsigned long long u; } o;
    o.h[0] = __float2bfloat16(v.x);
    o.h[1] = __float2bfloat16(v.y);
    o.h[2] = __float2bfloat16(v.z);
    o.h[3] = __float2bfloat16(v.w);
    *(unsigned long long*)(cd.d[e] + base) = o.u;
}

__global__ __launch_bounds__(256) void extract_k(
    const float* __restrict__ w1, const float* __restrict__ saw,
    bf16* __restrict__ w1c, float* __restrict__ sac)
{
    const int idx = blockIdx.x * 256 + threadIdx.x;
    if (idx < 384 * 768){
        const int oc = idx / 768, ic = idx % 768;
        w1c[idx] = __float2bfloat16(w1[(size_t)oc * 6912 + (size_t)ic * 9 + 4]);
    }
    if (idx < 384) sac[idx] = saw[(size_t)idx * 49 + 24];
}

// ---------------------------------------------------------------------------
// Fused FDA tail: per row x1 (384 ch, bf16 in/out):
//   ca1 = gelu(Wc1 @ x1)            (24)
//   ca2 = sigmoid(Wc2 @ ca1)        (384)
//   x2  = x1 * ca2
//   sa  = sigmoid(<x2, sac> + sab); x3 = x2 * sa
//   xg  = gelu(<x3, decw> + decb);  x4 = x3 + sigma*(x3 - xg)
// Weights fp32, L2-resident (73 KB). One 128-thread block per row.
// ---------------------------------------------------------------------------
__global__ __launch_bounds__(128) void fda_fused_k(
    bf16* __restrict__ x, const float* __restrict__ wc1, const float* __restrict__ wc2,
    const float* __restrict__ sac, const float* __restrict__ sab,
    const float* __restrict__ decw, const float* __restrict__ decb,
    const float* __restrict__ sigma)
{
    __shared__ float xs[384];
    __shared__ float ca1s[24];
    __shared__ float red[128];
    const int b = blockIdx.x;
    const int tid = threadIdx.x;
    bf16* xr = x + (size_t)b * 384;
    #pragma unroll
    for (int i = 0; i < 3; ++i) xs[tid + i * 128] = cvt(xr[tid + i * 128]);
    __syncthreads();
    // ca1: 24 outputs x 4 lanes each (t<96), 96 MACs per lane, 4-lane reduce
    if (tid < 96){
        const int o = tid >> 2, sub = tid & 3;
        const float* w = wc1 + (size_t)o * 384 + sub * 96;
        float p = 0.f;
        #pragma unroll 8
        for (int k = 0; k < 96; ++k) p = fmaf(xs[sub * 96 + k], w[k], p);
        p += __shfl_down(p, 1, 64);
        p += __shfl_down(p, 2, 64);
        if (sub == 0) ca1s[o] = gelu_f(p);
    }
    __syncthreads();
    // ca2 + pointwise
    float x2[3];
    float p = 0.f;
    #pragma unroll
    for (int i = 0; i < 3; ++i){
        const int c = tid + i * 128;
        float s = 0.f;
        const float* w = wc2 + (size_t)c * 24;
        #pragma unroll
        for (int k = 0; k < 24; ++k) s = fmaf(ca1s[k], w[k], s);
        const float v = xs[c] * sigmoid_f(s);
        x2[i] = v;
        p += v * sac[c];
    }
    red[tid] = p; __syncthreads();
    for (int s = 64; s > 0; s >>= 1){ if (tid < s) red[tid] += red[tid + s]; __syncthreads(); }
    const float sa = sigmoid_f(red[0] + sab[0]);
    __syncthreads();
    float q = 0.f;
    #pragma unroll
    for (int i = 0; i < 3; ++i){
        const int c = tid + i * 128;
        x2[i] *= sa;
        q += x2[i] * decw[c];
    }
    red[tid] = q; __syncthreads();
    for (int s = 64; s > 0; s >>= 1){ if (tid < s) red[tid] += red[tid + s]; __syncthreads(); }
    const float xg = gelu_f(red[0] + decb[0]);
    #pragma unroll
    for (int i = 0; i < 3; ++i){
        const int c = tid + i * 128;
        const float sg = sigma[c];
        stv(&xr[c], x2[i] + sg * (x2[i] - xg));
    }
}

// Row softmax: one block per 4096-wide row, 16 elems/thread, vectorized
__global__ __launch_bounds__(256) void softmax_rows_k(bf16* __restrict__ S)
{
    __shared__ float red[256];
    const int tid = threadIdx.x;
    u16* r = (u16*)(S + (size_t)blockIdx.x * NB) + tid * 16;
    u16x8 h0 = *(const u16x8*)r;
    u16x8 h1 = *(const u16x8*)(r + 8);
    float v[16];
    #pragma unroll
    for (int i = 0; i < 8; ++i){
        v[i]     = __uint_as_float((unsigned)h0[i] << 16);
        v[8 + i] = __uint_as_float((unsigned)h1[i] << 16);
    }
    float m = v[0];
    #pragma unroll
    for (int i = 1; i < 16; ++i) m = fmaxf(m, v[i]);
    red[tid] = m; __syncthreads();
    for (int s = 128; s > 0; s >>= 1){ if (tid < s) red[tid] = fmaxf(red[tid], red[tid + s]); __syncthreads(); }
    m = red[0]; __syncthreads();
    float sum = 0.f;
    #pragma unroll
    for (int i = 0; i < 16; ++i){ v[i] = expf(v[i] - m); sum += v[i]; }
    red[tid] = sum; __syncthreads();
    for (int s = 128; s > 0; s >>= 1){ if (tid < s) red[tid] += red[tid + s]; __syncthreads(); }
    const float inv = 1.0f / red[0];
    u16x8 o0, o1;
    #pragma unroll
    for (int i = 0; i < 8; ++i){
        o0[i] = __bfloat16_as_ushort(__float2bfloat16(v[i] * inv));
        o1[i] = __bfloat16_as_ushort(__float2bfloat16(v[8 + i] * inv));
    }
    *(u16x8*)r = o0;
    *(u16x8*)(r + 8) = o1;
}

// o1 = a+b ; o2 = c+d  (elementwise bf16, x8 vectorized)
__global__ __launch_bounds__(256) void reduce2_k(
    const bf16* __restrict__ a, const bf16* __restrict__ b, bf16* __restrict__ o1,
    const bf16* __restrict__ c, const bf16* __restrict__ d, bf16* __restrict__ o2)
{
    const size_t i = ((size_t)blockIdx.x * 256 + threadIdx.x) * 8;
    if (i >= (size_t)NB * DM) return;
    u16x8 ua = *(const u16x8*)((const u16*)a + i);
    u16x8 ub = *(const u16x8*)((const u16*)b + i);
    u16x8 uc = *(const u16x8*)((const u16*)c + i);
    u16x8 ud = *(const u16x8*)((const u16*)d + i);
    u16x8 r1, r2;
    #pragma unroll
    for (int j = 0; j < 8; ++j){
        const float s1 = __uint_as_float((unsigned)ua[j] << 16) + __uint_as_float((unsigned)ub[j] << 16);
        const float s2 = __uint_as_float((unsigned)uc[j] << 16) + __uint_as_float((unsigned)ud[j] << 16);
        r1[j] = __bfloat16_as_ushort(__float2bfloat16(s1));
        r2[j] = __bfloat16_as_ushort(__float2bfloat16(s2));
    }
    *(u16x8*)((u16*)o1 + i) = r1;
    *(u16x8*)((u16*)o2 + i) = r2;
}

// acc = sig(g1)*a1*s1 + sig(g2)*a2*s2
__global__ __launch_bounds__(256) void combine2_k(
    bf16* __restrict__ acc,
    const bf16* __restrict__ g1, const bf16* __restrict__ a1, const float* __restrict__ s1,
    const bf16* __restrict__ g2, const bf16* __restrict__ a2, const float* __restrict__ s2)
{
    const size_t idx = (size_t)blockIdx.x * 256 + threadIdx.x;
    if (idx >= (size_t)NB * DM) return;
    const int col = (int)(idx % DM);
    const float v = sigmoid_f(cvt(g1[idx])) * cvt(a1[idx]) * s1[col]
                  + sigmoid_f(cvt(g2[idx])) * cvt(a2[idx]) * s2[col];
    stv(&acc[idx], v);
}

__global__ __launch_bounds__(64) void cls_softmax_k(
    const bf16* __restrict__ acc, const float* __restrict__ w,
    const float* __restrict__ bias, float* __restrict__ out)
{
    const int b = blockIdx.x;
    const bf16* r = acc + (size_t)b * DM;
    float p0 = 0.f, p1 = 0.f, p2 = 0.f;
    for (int k = threadIdx.x; k < DM; k += 64){
        const float v = cvt(r[k]);
        p0 = fmaf(v, w[k],        p0);
        p1 = fmaf(v, w[DM + k],   p1);
        p2 = fmaf(v, w[2*DM + k], p2);
    }
    #pragma unroll
    for (int off = 32; off > 0; off >>= 1){
        p0 += __shfl_down(p0, off, 64);
        p1 += __shfl_down(p1, off, 64);
        p2 += __shfl_down(p2, off, 64);
    }
    if (threadIdx.x == 0){
        const float l0 = p0 + bias[0];
        const float l1 = p1 + bias[1];
        const float l2 = p2 + bias[2];
        const float mx = fmaxf(l0, fmaxf(l1, l2));
        const float e0 = expf(l0 - mx), e1 = expf(l1 - mx), e2 = expf(l2 - mx);
        const float inv = 1.f / (e0 + e1 + e2);
        out[(size_t)b * 3 + 0] = e0 * inv;
        out[(size_t)b * 3 + 1] = e1 * inv;
        out[(size_t)b * 3 + 2] = e2 * inv;
    }
}

extern "C" void kernel_launch(void* const* d_in, const int* in_sizes, int n_in,
                              void* d_out, int out_size, void* d_ws, size_t ws_size,
                              hipStream_t stream)
{
    const float* text   = (const float*)d_in[0];
    const float* image  = (const float*)d_in[1];
    const float* tl_w   = (const float*)d_in[2];
    const float* tl_b   = (const float*)d_in[3];
    const float* il_w   = (const float*)d_in[4];
    const float* il_b   = (const float*)d_in[5];
    const float* sda_wv = (const float*)d_in[10];
    const float* sda_bv = (const float*)d_in[11];
    const float* sda_wo = (const float*)d_in[12];
    const float* sda_bo = (const float*)d_in[13];
    const float* fda_w1 = (const float*)d_in[14];
    const float* fda_b1 = (const float*)d_in[15];
    const float* bn1_g  = (const float*)d_in[16];
    const float* bn1_b  = (const float*)d_in[17];
    const float* ca_w1  = (const float*)d_in[18];
    const float* ca_w2  = (const float*)d_in[19];
    const float* sa_w   = (const float*)d_in[20];
    const float* sa_b   = (const float*)d_in[21];
    const float* dec_w  = (const float*)d_in[22];
    const float* dec_b  = (const float*)d_in[23];
    const float* sigma  = (const float*)d_in[24];
    const float* fda_wf = (const float*)d_in[25];
    const float* fda_bf = (const float*)d_in[26];
    const float* bn2_g  = (const float*)d_in[27];
    const float* bn2_b  = (const float*)d_in[28];
    const float* dmi_wq = (const float*)d_in[29];
    const float* dmi_bq = (const float*)d_in[30];
    const float* dmi_wk = (const float*)d_in[31];
    const float* dmi_bk = (const float*)d_in[32];
    const float* dmi_wv = (const float*)d_in[33];
    const float* dmi_bv = (const float*)d_in[34];
    const float* tg_w1  = (const float*)d_in[35];
    const float* tg_b1  = (const float*)d_in[36];
    const float* tg_w2  = (const float*)d_in[37];
    const float* tg_b2  = (const float*)d_in[38];
    const float* ig_w1  = (const float*)d_in[39];
    const float* ig_b1  = (const float*)d_in[40];
    const float* ig_w2  = (const float*)d_in[41];
    const float* ig_b2  = (const float*)d_in[42];
    const float* t_scale= (const float*)d_in[43];
    const float* i_scale= (const float*)d_in[44];
    const float* cls_w  = (const float*)d_in[45];
    const float* cls_b  = (const float*)d_in[46];
    float* out = (float*)d_out;

    // ---- workspace (~128 MB, identical footprint to the R5 full path) ----
    char* base = (char*)d_ws;
    auto alloc = [&](size_t bytes){ void* p = (void*)base; base += (bytes + 255) & ~(size_t)255; return p; };
    const size_t SLOT = (size_t)NB * DM;
    const size_t W768 = (size_t)768 * 768;
    bf16* tl_wb   = (bf16*)alloc(W768 * 2);
    bf16* il_wb   = (bf16*)alloc(W768 * 2);
    bf16* sda_wvb = (bf16*)alloc((size_t)512 * 768 * 2);
    bf16* sda_wob = (bf16*)alloc((size_t)768 * 512 * 2);
    bf16* fda_wfb = (bf16*)alloc((size_t)768 * 384 * 2);
    bf16* dmi_wqb = (bf16*)alloc(W768 * 2);
    bf16* dmi_wkb = (bf16*)alloc(W768 * 2);
    bf16* dmi_wvb = (bf16*)alloc(W768 * 2);
    bf16* tg_w1b  = (bf16*)alloc(W768 * 2);
    bf16* tg_w2b  = (bf16*)alloc(W768 * 2);
    bf16* ig_w1b  = (bf16*)alloc(W768 * 2);
    bf16* ig_w2b  = (bf16*)alloc(W768 * 2);
    bf16* w1c     = (bf16*)alloc((size_t)384 * 768 * 2);
    float* sac    = (float*)alloc(1536 * 4);
    bf16* SL[8];
    for (int i = 0; i < 8; ++i) SL[i] = (bf16*)alloc(SLOT * 2);
    bf16* SC1 = (bf16*)alloc((size_t)NB * NB * 2);
    bf16* SC2 = (bf16*)alloc((size_t)NB * NB * 2);   // contiguous after SC1 (32 MB each)

    const float bnscale = 1.0f / sqrtf(1.0f + 1e-5f);
    const float iscale  = 1.0f / sqrtf(768.0f);
    const dim3 blk(256);

    // job-batch builder
    struct JB {
        Jobs jb; int blocks;
        void add(const bf16* A, const bf16* B, bf16* C, int M, int N, int K, int ldA, int ldB,
                 const float* b0, float al, const float* gv, const float* b1, int act, int trans){
            Job& j = jb.j[jb.nj++];
            j.A=A; j.B=B; j.C=C; j.b0=b0; j.gv=gv; j.b1=b1;
            j.M=M; j.N=N; j.K=K; j.ldA=ldA; j.ldB=ldB; j.act=act; j.trans=trans;
            j.alpha=al; j.blk0=blocks; j.nx=N/128;
            blocks += (N/128)*(M/128);
        }
    };
    auto launch = [&](JB& b){ mgemm_k<<<dim3(b.blocks), blk, 0, stream>>>(b.jb); };

    // fp32 -> bf16 staging (inputs into SL0/SL1, weights into *_b)
    CvtDesc cd;
    const float* srcs[NCVT] = {text, image, tl_w, il_w, sda_wv, sda_wo, fda_wf,
                               dmi_wq, dmi_wk, dmi_wv, tg_w1, tg_w2, ig_w1, ig_w2};
    bf16* dsts[NCVT] = {SL[0], SL[1], tl_wb, il_wb, sda_wvb, sda_wob, fda_wfb,
                        dmi_wqb, dmi_wkb, dmi_wvb, tg_w1b, tg_w2b, ig_w1b, ig_w2b};
    int   lens[NCVT] = {(int)SLOT, (int)SLOT, (int)W768, (int)W768, 512*768, 768*512, 768*384,
                        (int)W768, (int)W768, (int)W768, (int)W768, (int)W768, (int)W768, (int)W768};
    for (int i = 0; i < NCVT; ++i){ cd.s[i] = srcs[i]; cd.d[i] = dsts[i]; cd.n[i] = lens[i]; }
    cvt_k<<<dim3((int)(SLOT / 1024), NCVT), blk, 0, stream>>>(cd);
    extract_k<<<dim3((384 * 768 + 255) / 256), blk, 0, stream>>>(fda_w1, sa_w, w1c, sac);

    // J1: t0 = gelu(text@tl^T) -> SL2 ; im0 = gelu(image@il^T) -> SL3
    { JB b{}; b.add(SL[0], tl_wb, SL[2], NB, DM, DM, DM, DM, tl_b, 1.f, nullptr, nullptr, 1, 0);
              b.add(SL[1], il_wb, SL[3], NB, DM, DM, DM, DM, il_b, 1.f, nullptr, nullptr, 1, 0); launch(b); }
    // J2 (independent branches): wv = t0@wv^T -> SL0 (N=512) ; x1 = conv1(im0) -> SL1 (N=384)
    { JB b{}; b.add(SL[2], sda_wvb, SL[0], NB, 512, DM, DM, DM, sda_bv, 1.f, nullptr, nullptr, 0, 0);
              b.add(SL[3], w1c,     SL[1], NB, 384, DM, DM, DM, fda_b1, bnscale, bn1_g, bn1_b, 1, 0); launch(b); }
    // J3: t1 = wv@wo^T -> SL4 (K=512, A row-stride 512)
    { JB b{}; b.add(SL[0], sda_wob, SL[4], NB, DM, 512, 512, 512, sda_bo, 1.f, nullptr, nullptr, 0, 0); launch(b); }
    // fused FDA tail (in place on SL1)
    fda_fused_k<<<dim3(NB), dim3(128), 0, stream>>>(SL[1], ca_w1, ca_w2, sac, sa_b, dec_w, dec_b, sigma);
    // J4: im1 = gelu((x4@wf^T + bf)*bn2) -> SL5 (K=384)
    { JB b{}; b.add(SL[1], fda_wfb, SL[5], NB, DM, 384, 384, 384, fda_bf, bnscale, bn2_g, bn2_b, 1, 0); launch(b); }

    // J5: QKV both directions (6 jobs): Q1->SL0 K1->SL1 V1t->SL2 Q2->SL3 K2->SL6 V2t->SL7
    { JB b{};
      b.add(SL[4], dmi_wqb, SL[0], NB, DM, DM, DM, DM, dmi_bq, 1.f, nullptr, nullptr, 0, 0);
      b.add(SL[5], dmi_wkb, SL[1], NB, DM, DM, DM, DM, dmi_bk, 1.f, nullptr, nullptr, 0, 0);
      b.add(SL[5], dmi_wvb, SL[2], NB, DM, DM, DM, DM, dmi_bv, 1.f, nullptr, nullptr, 0, 1);
      b.add(SL[5], dmi_wqb, SL[3], NB, DM, DM, DM, DM, dmi_bq, 1.f, nullptr, nullptr, 0, 0);
      b.add(SL[4], dmi_wkb, SL[6], NB, DM, DM, DM, DM, dmi_bk, 1.f, nullptr, nullptr, 0, 0);
      b.add(SL[4], dmi_wvb, SL[7], NB, DM, DM, DM, DM, dmi_bv, 1.f, nullptr, nullptr, 0, 1);
      launch(b); }
    // J6: scores (2 jobs, 2048 blocks)
    { JB b{}; b.add(SL[0], SL[1], SC1, NB, NB, DM, DM, DM, nullptr, iscale, nullptr, nullptr, 0, 0);
              b.add(SL[3], SL[6], SC2, NB, NB, DM, DM, DM, nullptr, iscale, nullptr, nullptr, 0, 0); launch(b); }
    softmax_rows_k<<<dim3(2 * NB), blk, 0, stream>>>(SC1);   // SC2 contiguous
    // J7: PV split-K=2 x 2 dirs (4 jobs, 768 blocks); partials into dead Q/K slots
    { JB b{};
      b.add(SC1,        SL[2],        SL[0], NB, DM, 2048, NB, NB, nullptr, 1.f, nullptr, nullptr, 0, 0);
      b.add(SC1 + 2048, SL[2] + 2048, SL[1], NB, DM, 2048, NB, NB, nullptr, 1.f, nullptr, nullptr, 0, 0);
      b.add(SC2,        SL[7],        SL[3], NB, DM, 2048, NB, NB, nullptr, 1.f, nullptr, nullptr, 0, 0);
      b.add(SC2 + 2048, SL[7] + 2048, SL[6], NB, DM, 2048, NB, NB, nullptr, 1.f, nullptr, nullptr, 0, 0);
      launch(b); }
    // a1 = SL0+SL1 -> SL4 ; a2 = SL3+SL6 -> SL5
    reduce2_k<<<dim3((int)(SLOT / 2048)), blk, 0, stream>>>(SL[0], SL[1], SL[4], SL[3], SL[6], SL[5]);
    // J8: gate hidden (relu) ; J9: gate out (sigmoid)
    { JB b{}; b.add(SL[4], tg_w1b, SL[0], NB, DM, DM, DM, DM, tg_b1, 1.f, nullptr, nullptr, 3, 0);
              b.add(SL[5], ig_w1b, SL[1], NB, DM, DM, DM, DM, ig_b1, 1.f, nullptr, nullptr, 3, 0); launch(b); }
    { JB b{}; b.add(SL[0], tg_w2b, SL[3], NB, DM, DM, DM, DM, tg_b2, 1.f, nullptr, nullptr, 2, 0);
              b.add(SL[1], ig_w2b, SL[6], NB, DM, DM, DM, DM, ig_b2, 1.f, nullptr, nullptr, 2, 0); launch(b); }
    combine2_k<<<dim3((NB * DM + 255) / 256), blk, 0, stream>>>(SL[2], SL[3], SL[4], t_scale, SL[6], SL[5], i_scale);
    cls_softmax_k<<<dim3(NB), dim3(64), 0, stream>>>(SL[2], cls_w, cls_b, out);
}

// Round 7
// 600.406 us; speedup vs baseline: 12.2096x; 1.0949x over previous
//
#include <hip/hip_runtime.h>
#include <hip/hip_bf16.h>
#include <math.h>

typedef __hip_bfloat16 bf16;
typedef __bf16 bf16x8 __attribute__((ext_vector_type(8)));
typedef float f32x4 __attribute__((ext_vector_type(4)));
typedef unsigned short u16;
typedef u16 u16x8 __attribute__((ext_vector_type(8)));

#define NB 4096          // batch rows
#define DM 768           // model dim

__device__ __forceinline__ float cvt(float x){ return x; }
__device__ __forceinline__ float cvt(bf16 x){ return __bfloat162float(x); }
__device__ __forceinline__ void stv(float* p, float v){ *p = v; }
__device__ __forceinline__ void stv(bf16* p, float v){ *p = __float2bfloat16(v); }

__device__ __forceinline__ float gelu_f(float x){
    return 0.5f * x * (1.0f + erff(x * 0.70710678118654752440f));
}
__device__ __forceinline__ float sigmoid_f(float x){
    return 1.0f / (1.0f + expf(-x));
}

__device__ __forceinline__ void async_copy16(const void* g, void* l){
    __builtin_amdgcn_global_load_lds((const __attribute__((address_space(1))) void*)g,
                                     (__attribute__((address_space(3))) void*)l, 16, 0, 0);
}

// ---------------------------------------------------------------------------
// Flat multi-job MFMA GEMM. Per job: C = act((A @ Bm^T + b0) * alpha * gv + b1)
// A: (M,ldA) bf16 cols [0,K). Bm: (N,ldB) bf16 (B^T layout) cols [0,K).
// M%128==0, N%128==0, K%64==0. trans=1: store C^T into (N,M).
// BK=64 (32 MFMA per barrier), XOR-chunk LDS swizzle, LDS-staged coalesced
// epilogue stores (256 B lines).
// ---------------------------------------------------------------------------
#define MAXJ 8
struct Job {
    const bf16* A; const bf16* B; bf16* C;
    const float* b0; const float* gv; const float* b1;
    int M, N, K, ldA, ldB, act, trans, blk0, nx;
    float alpha;
};
struct Jobs { Job j[MAXJ]; int nj; };

__global__ __launch_bounds__(256) void mgemm_k(Jobs jb)
{
    int z = 0;
    #pragma unroll
    for (int i = 1; i < MAXJ; ++i)
        if (i < jb.nj && (int)blockIdx.x >= jb.j[i].blk0) z = i;
    const Job& J = jb.j[z];
    const bf16* __restrict__ A  = J.A;
    const bf16* __restrict__ Bm = J.B;
    bf16* __restrict__ C        = J.C;
    const int bx = (int)blockIdx.x - J.blk0;
    const int gx = bx % J.nx;
    const int gy = bx / J.nx;
    const int M = J.M, N = J.N, K = J.K, ldA = J.ldA, ldB = J.ldB;

    // staging: A = smem[0 .. 8191] (128x64), B = smem[8192 .. 16383]
    // epilogue: 128x136 bf16 tile = 17408 elems
    __shared__ __align__(16) bf16 smem[17408];
    const int tid  = threadIdx.x;
    const int wave = tid >> 6;
    const int lane = tid & 63;
    const int row0 = gy * 128;
    const int col0 = gx * 128;
    const int wrow = (wave & 1) * 64;
    const int wcol = (wave >> 1) * 64;
    const int fl   = lane & 15;
    const int q    = lane >> 4;

    // staging addressing: per instr a wave stages 8 rows x 64 cols (1 KiB).
    // phys chunk (lane&7) at row r holds logical chunk (lane&7)^(r&7).
    const int sr8 = lane >> 3;                       // row within 8-row group
    const int sc8 = (((lane & 7) ^ sr8)) * 8;        // swizzled source col
    const bf16* pA = A  + (size_t)(row0 + wave * 32 + sr8) * ldA + sc8;
    const bf16* pB = Bm + (size_t)(col0 + wave * 32 + sr8) * ldB + sc8;
    bf16* ldsA = &smem[(wave * 32) * 64];
    bf16* ldsB = &smem[8192 + (wave * 32) * 64];

    f32x4 acc[4][4] = {};
    for (int k0 = 0; k0 < K; k0 += 64){
        #pragma unroll
        for (int i = 0; i < 4; ++i){
            async_copy16(pA + (size_t)(i * 8) * ldA, ldsA + i * 512);
            async_copy16(pB + (size_t)(i * 8) * ldB, ldsB + i * 512);
        }
        pA += 64; pB += 64;
        __syncthreads();
        #pragma unroll
        for (int ks = 0; ks < 2; ++ks){
            bf16x8 af[4], bfv[4];
            #pragma unroll
            for (int i = 0; i < 4; ++i){
                const int ra = wrow + i * 16 + fl;
                const int rb = wcol + i * 16 + fl;
                const int ca = ((ks * 4 + q) ^ (ra & 7)) * 8;
                const int cb = ((ks * 4 + q) ^ (rb & 7)) * 8;
                af[i]  = *(const bf16x8*)&smem[ra * 64 + ca];
                bfv[i] = *(const bf16x8*)&smem[8192 + rb * 64 + cb];
            }
            #pragma unroll
            for (int mi = 0; mi < 4; ++mi)
                #pragma unroll
                for (int ni = 0; ni < 4; ++ni)
                    acc[mi][ni] = __builtin_amdgcn_mfma_f32_16x16x32_bf16(af[mi], bfv[ni], acc[mi][ni], 0, 0, 0);
        }
        __syncthreads();
    }

    // epilogue: C/D layout col = lane&15, row = q*4 + reg (verified R4-R6)
    // stage to LDS (padded ld=136), then block-wide 256 B coalesced stores.
    constexpr int ELD = 136;
    #pragma unroll
    for (int ni = 0; ni < 4; ++ni){
        const int col = col0 + wcol + ni * 16 + fl;
        const float b0 = J.b0 ? J.b0[col] : 0.f;
        const float gm = (J.gv ? J.gv[col] : 1.f) * J.alpha;
        const float b1 = J.b1 ? J.b1[col] : 0.f;
        const int lcol = wcol + ni * 16 + fl;
        #pragma unroll
        for (int mi = 0; mi < 4; ++mi){
            const int lrow = wrow + mi * 16 + q * 4;
            #pragma unroll
            for (int r = 0; r < 4; ++r){
                float v = (acc[mi][ni][r] + b0) * gm + b1;
                if      (J.act == 1) v = gelu_f(v);
                else if (J.act == 2) v = sigmoid_f(v);
                else if (J.act == 3) v = fmaxf(v, 0.f);
                if (J.trans) smem[(size_t)lcol * ELD + lrow + r] = __float2bfloat16(v);
                else         smem[(size_t)(lrow + r) * ELD + lcol] = __float2bfloat16(v);
            }
        }
    }
    __syncthreads();
    const int erow = tid >> 4;         // 0..15
    const int ecol = (tid & 15) * 8;   // element offset, 16 B
    #pragma unroll
    for (int p = 0; p < 8; ++p){
        const int row = p * 16 + erow;
        const bf16x8 val = *(const bf16x8*)&smem[row * ELD + ecol];
        if (J.trans) *(bf16x8*)&C[(size_t)(col0 + row) * M + row0 + ecol] = val;
        else         *(bf16x8*)&C[(size_t)(row0 + row) * N + col0 + ecol] = val;
    }
}

// Batched fp32 -> bf16 conversion
#define NCVT 14
struct CvtDesc { const float* s[NCVT]; bf16* d[NCVT]; int n[NCVT]; };
__global__ __launch_bounds__(256) void cvt_k(CvtDesc cd)
{
    const int e = blockIdx.y;
    const int base = (blockIdx.x * 256 + threadIdx.x) * 4;
    if (base >= cd.n[e]) return;
    const float4 v = *(const float4*)(cd.s[e] + base);
    union { bf16 h[4]; unsigned long long u; } o;
    o.h[0] = __float2bfloat16(v.x);
    o.h[1] = __float2bfloat16(v.y);
    o.h[2] = __float2bfloat16(v.z);
    o.h[3] = __float2bfloat16(v.w);
    *(unsigned long long*)(cd.d[e] + base) = o.u;
}

__global__ __launch_bounds__(256) void extract_k(
    const float* __restrict__ w1, const float* __restrict__ saw,
    bf16* __restrict__ w1c, float* __restrict__ sac)
{
    const int idx = blockIdx.x * 256 + threadIdx.x;
    if (idx < 384 * 768){
        const int oc = idx / 768, ic = idx % 768;
        w1c[idx] = __float2bfloat16(w1[(size_t)oc * 6912 + (size_t)ic * 9 + 4]);
    }
    if (idx < 384) sac[idx] = saw[(size_t)idx * 49 + 24];
}

// Fused FDA tail (see R6): ca1 -> ca2 -> x2 -> sa -> x3 -> dec -> x4, in place
__global__ __launch_bounds__(128) void fda_fused_k(
    bf16* __restrict__ x, const float* __restrict__ wc1, const float* __restrict__ wc2,
    const float* __restrict__ sac, const float* __restrict__ sab,
    const float* __restrict__ decw, const float* __restrict__ decb,
    const float* __restrict__ sigma)
{
    __shared__ float xs[384];
    __shared__ float ca1s[24];
    __shared__ float red[128];
    const int b = blockIdx.x;
    const int tid = threadIdx.x;
    bf16* xr = x + (size_t)b * 384;
    #pragma unroll
    for (int i = 0; i < 3; ++i) xs[tid + i * 128] = cvt(xr[tid + i * 128]);
    __syncthreads();
    if (tid < 96){
        const int o = tid >> 2, sub = tid & 3;
        const float* w = wc1 + (size_t)o * 384 + sub * 96;
        float p = 0.f;
        #pragma unroll 8
        for (int k = 0; k < 96; ++k) p = fmaf(xs[sub * 96 + k], w[k], p);
        p += __shfl_down(p, 1, 64);
        p += __shfl_down(p, 2, 64);
        if (sub == 0) ca1s[o] = gelu_f(p);
    }
    __syncthreads();
    float x2[3];
    float p = 0.f;
    #pragma unroll
    for (int i = 0; i < 3; ++i){
        const int c = tid + i * 128;
        float s = 0.f;
        const float* w = wc2 + (size_t)c * 24;
        #pragma unroll
        for (int k = 0; k < 24; ++k) s = fmaf(ca1s[k], w[k], s);
        const float v = xs[c] * sigmoid_f(s);
        x2[i] = v;
        p += v * sac[c];
    }
    red[tid] = p; __syncthreads();
    for (int s = 64; s > 0; s >>= 1){ if (tid < s) red[tid] += red[tid + s]; __syncthreads(); }
    const float sa = sigmoid_f(red[0] + sab[0]);
    __syncthreads();
    float qq = 0.f;
    #pragma unroll
    for (int i = 0; i < 3; ++i){
        const int c = tid + i * 128;
        x2[i] *= sa;
        qq += x2[i] * decw[c];
    }
    red[tid] = qq; __syncthreads();
    for (int s = 64; s > 0; s >>= 1){ if (tid < s) red[tid] += red[tid + s]; __syncthreads(); }
    const float xg = gelu_f(red[0] + decb[0]);
    #pragma unroll
    for (int i = 0; i < 3; ++i){
        const int c = tid + i * 128;
        const float sg = sigma[c];
        stv(&xr[c], x2[i] + sg * (x2[i] - xg));
    }
}

// Row softmax: one block per 4096-wide row, 16 elems/thread, vectorized
__global__ __launch_bounds__(256) void softmax_rows_k(bf16* __restrict__ S)
{
    __shared__ float red[256];
    const int tid = threadIdx.x;
    u16* r = (u16*)(S + (size_t)blockIdx.x * NB) + tid * 16;
    u16x8 h0 = *(const u16x8*)r;
    u16x8 h1 = *(const u16x8*)(r + 8);
    float v[16];
    #pragma unroll
    for (int i = 0; i < 8; ++i){
        v[i]     = __uint_as_float((unsigned)h0[i] << 16);
        v[8 + i] = __uint_as_float((unsigned)h1[i] << 16);
    }
    float m = v[0];
    #pragma unroll
    for (int i = 1; i < 16; ++i) m = fmaxf(m, v[i]);
    red[tid] = m; __syncthreads();
    for (int s = 128; s > 0; s >>= 1){ if (tid < s) red[tid] = fmaxf(red[tid], red[tid + s]); __syncthreads(); }
    m = red[0]; __syncthreads();
    float sum = 0.f;
    #pragma unroll
    for (int i = 0; i < 16; ++i){ v[i] = expf(v[i] - m); sum += v[i]; }
    red[tid] = sum; __syncthreads();
    for (int s = 128; s > 0; s >>= 1){ if (tid < s) red[tid] += red[tid + s]; __syncthreads(); }
    const float inv = 1.0f / red[0];
    u16x8 o0, o1;
    #pragma unroll
    for (int i = 0; i < 8; ++i){
        o0[i] = __bfloat16_as_ushort(__float2bfloat16(v[i] * inv));
        o1[i] = __bfloat16_as_ushort(__float2bfloat16(v[8 + i] * inv));
    }
    *(u16x8*)r = o0;
    *(u16x8*)(r + 8) = o1;
}

// o1 = a+b ; o2 = c+d  (elementwise bf16, x8 vectorized)
__global__ __launch_bounds__(256) void reduce2_k(
    const bf16* __restrict__ a, const bf16* __restrict__ b, bf16* __restrict__ o1,
    const bf16* __restrict__ c, const bf16* __restrict__ d, bf16* __restrict__ o2)
{
    const size_t i = ((size_t)blockIdx.x * 256 + threadIdx.x) * 8;
    if (i >= (size_t)NB * DM) return;
    u16x8 ua = *(const u16x8*)((const u16*)a + i);
    u16x8 ub = *(const u16x8*)((const u16*)b + i);
    u16x8 uc = *(const u16x8*)((const u16*)c + i);
    u16x8 ud = *(const u16x8*)((const u16*)d + i);
    u16x8 r1, r2;
    #pragma unroll
    for (int j = 0; j < 8; ++j){
        const float s1 = __uint_as_float((unsigned)ua[j] << 16) + __uint_as_float((unsigned)ub[j] << 16);
        const float s2 = __uint_as_float((unsigned)uc[j] << 16) + __uint_as_float((unsigned)ud[j] << 16);
        r1[j] = __bfloat16_as_ushort(__float2bfloat16(s1));
        r2[j] = __bfloat16_as_ushort(__float2bfloat16(s2));
    }
    *(u16x8*)((u16*)o1 + i) = r1;
    *(u16x8*)((u16*)o2 + i) = r2;
}

// acc = sig(g1)*a1*s1 + sig(g2)*a2*s2
__global__ __launch_bounds__(256) void combine2_k(
    bf16* __restrict__ acc,
    const bf16* __restrict__ g1, const bf16* __restrict__ a1, const float* __restrict__ s1,
    const bf16* __restrict__ g2, const bf16* __restrict__ a2, const float* __restrict__ s2)
{
    const size_t idx = (size_t)blockIdx.x * 256 + threadIdx.x;
    if (idx >= (size_t)NB * DM) return;
    const int col = (int)(idx % DM);
    const float v = sigmoid_f(cvt(g1[idx])) * cvt(a1[idx]) * s1[col]
                  + sigmoid_f(cvt(g2[idx])) * cvt(a2[idx]) * s2[col];
    stv(&acc[idx], v);
}

__global__ __launch_bounds__(64) void cls_softmax_k(
    const bf16* __restrict__ acc, const float* __restrict__ w,
    const float* __restrict__ bias, float* __restrict__ out)
{
    const int b = blockIdx.x;
    const bf16* r = acc + (size_t)b * DM;
    float p0 = 0.f, p1 = 0.f, p2 = 0.f;
    for (int k = threadIdx.x; k < DM; k += 64){
        const float v = cvt(r[k]);
        p0 = fmaf(v, w[k],        p0);
        p1 = fmaf(v, w[DM + k],   p1);
        p2 = fmaf(v, w[2*DM + k], p2);
    }
    #pragma unroll
    for (int off = 32; off > 0; off >>= 1){
        p0 += __shfl_down(p0, off, 64);
        p1 += __shfl_down(p1, off, 64);
        p2 += __shfl_down(p2, off, 64);
    }
    if (threadIdx.x == 0){
        const float l0 = p0 + bias[0];
        const float l1 = p1 + bias[1];
        const float l2 = p2 + bias[2];
        const float mx = fmaxf(l0, fmaxf(l1, l2));
        const float e0 = expf(l0 - mx), e1 = expf(l1 - mx), e2 = expf(l2 - mx);
        const float inv = 1.f / (e0 + e1 + e2);
        out[(size_t)b * 3 + 0] = e0 * inv;
        out[(size_t)b * 3 + 1] = e1 * inv;
        out[(size_t)b * 3 + 2] = e2 * inv;
    }
}

extern "C" void kernel_launch(void* const* d_in, const int* in_sizes, int n_in,
                              void* d_out, int out_size, void* d_ws, size_t ws_size,
                              hipStream_t stream)
{
    const float* text   = (const float*)d_in[0];
    const float* image  = (const float*)d_in[1];
    const float* tl_w   = (const float*)d_in[2];
    const float* tl_b   = (const float*)d_in[3];
    const float* il_w   = (const float*)d_in[4];
    const float* il_b   = (const float*)d_in[5];
    const float* sda_wv = (const float*)d_in[10];
    const float* sda_bv = (const float*)d_in[11];
    const float* sda_wo = (const float*)d_in[12];
    const float* sda_bo = (const float*)d_in[13];
    const float* fda_w1 = (const float*)d_in[14];
    const float* fda_b1 = (const float*)d_in[15];
    const float* bn1_g  = (const float*)d_in[16];
    const float* bn1_b  = (const float*)d_in[17];
    const float* ca_w1  = (const float*)d_in[18];
    const float* ca_w2  = (const float*)d_in[19];
    const float* sa_w   = (const float*)d_in[20];
    const float* sa_b   = (const float*)d_in[21];
    const float* dec_w  = (const float*)d_in[22];
    const float* dec_b  = (const float*)d_in[23];
    const float* sigma  = (const float*)d_in[24];
    const float* fda_wf = (const float*)d_in[25];
    const float* fda_bf = (const float*)d_in[26];
    const float* bn2_g  = (const float*)d_in[27];
    const float* bn2_b  = (const float*)d_in[28];
    const float* dmi_wq = (const float*)d_in[29];
    const float* dmi_bq = (const float*)d_in[30];
    const float* dmi_wk = (const float*)d_in[31];
    const float* dmi_bk = (const float*)d_in[32];
    const float* dmi_wv = (const float*)d_in[33];
    const float* dmi_bv = (const float*)d_in[34];
    const float* tg_w1  = (const float*)d_in[35];
    const float* tg_b1  = (const float*)d_in[36];
    const float* tg_w2  = (const float*)d_in[37];
    const float* tg_b2  = (const float*)d_in[38];
    const float* ig_w1  = (const float*)d_in[39];
    const float* ig_b1  = (const float*)d_in[40];
    const float* ig_w2  = (const float*)d_in[41];
    const float* ig_b2  = (const float*)d_in[42];
    const float* t_scale= (const float*)d_in[43];
    const float* i_scale= (const float*)d_in[44];
    const float* cls_w  = (const float*)d_in[45];
    const float* cls_b  = (const float*)d_in[46];
    float* out = (float*)d_out;

    // ---- workspace (~128 MB, same footprint as R5/R6) ----
    char* base = (char*)d_ws;
    auto alloc = [&](size_t bytes){ void* p = (void*)base; base += (bytes + 255) & ~(size_t)255; return p; };
    const size_t SLOT = (size_t)NB * DM;
    const size_t W768 = (size_t)768 * 768;
    bf16* tl_wb   = (bf16*)alloc(W768 * 2);
    bf16* il_wb   = (bf16*)alloc(W768 * 2);
    bf16* sda_wvb = (bf16*)alloc((size_t)512 * 768 * 2);
    bf16* sda_wob = (bf16*)alloc((size_t)768 * 512 * 2);
    bf16* fda_wfb = (bf16*)alloc((size_t)768 * 384 * 2);
    bf16* dmi_wqb = (bf16*)alloc(W768 * 2);
    bf16* dmi_wkb = (bf16*)alloc(W768 * 2);
    bf16* dmi_wvb = (bf16*)alloc(W768 * 2);
    bf16* tg_w1b  = (bf16*)alloc(W768 * 2);
    bf16* tg_w2b  = (bf16*)alloc(W768 * 2);
    bf16* ig_w1b  = (bf16*)alloc(W768 * 2);
    bf16* ig_w2b  = (bf16*)alloc(W768 * 2);
    bf16* w1c     = (bf16*)alloc((size_t)384 * 768 * 2);
    float* sac    = (float*)alloc(1536 * 4);
    bf16* SL[8];
    for (int i = 0; i < 8; ++i) SL[i] = (bf16*)alloc(SLOT * 2);
    bf16* SC1 = (bf16*)alloc((size_t)NB * NB * 2);
    bf16* SC2 = (bf16*)alloc((size_t)NB * NB * 2);   // contiguous after SC1

    const float bnscale = 1.0f / sqrtf(1.0f + 1e-5f);
    const float iscale  = 1.0f / sqrtf(768.0f);
    const dim3 blk(256);

    struct JB {
        Jobs jb; int blocks;
        void add(const bf16* A, const bf16* B, bf16* C, int M, int N, int K, int ldA, int ldB,
                 const float* b0, float al, const float* gv, const float* b1, int act, int trans){
            Job& j = jb.j[jb.nj++];
            j.A=A; j.B=B; j.C=C; j.b0=b0; j.gv=gv; j.b1=b1;
            j.M=M; j.N=N; j.K=K; j.ldA=ldA; j.ldB=ldB; j.act=act; j.trans=trans;
            j.alpha=al; j.blk0=blocks; j.nx=N/128;
            blocks += (N/128)*(M/128);
        }
    };
    auto launch = [&](JB& b){ mgemm_k<<<dim3(b.blocks), blk, 0, stream>>>(b.jb); };

    // fp32 -> bf16 staging
    CvtDesc cd;
    const float* srcs[NCVT] = {text, image, tl_w, il_w, sda_wv, sda_wo, fda_wf,
                               dmi_wq, dmi_wk, dmi_wv, tg_w1, tg_w2, ig_w1, ig_w2};
    bf16* dsts[NCVT] = {SL[0], SL[1], tl_wb, il_wb, sda_wvb, sda_wob, fda_wfb,
                        dmi_wqb, dmi_wkb, dmi_wvb, tg_w1b, tg_w2b, ig_w1b, ig_w2b};
    int   lens[NCVT] = {(int)SLOT, (int)SLOT, (int)W768, (int)W768, 512*768, 768*512, 768*384,
                        (int)W768, (int)W768, (int)W768, (int)W768, (int)W768, (int)W768, (int)W768};
    for (int i = 0; i < NCVT; ++i){ cd.s[i] = srcs[i]; cd.d[i] = dsts[i]; cd.n[i] = lens[i]; }
    cvt_k<<<dim3((int)(SLOT / 1024), NCVT), blk, 0, stream>>>(cd);
    extract_k<<<dim3((384 * 768 + 255) / 256), blk, 0, stream>>>(fda_w1, sa_w, w1c, sac);

    // J1: t0 = gelu(text@tl^T) -> SL2 ; im0 = gelu(image@il^T) -> SL3
    { JB b{}; b.add(SL[0], tl_wb, SL[2], NB, DM, DM, DM, DM, tl_b, 1.f, nullptr, nullptr, 1, 0);
              b.add(SL[1], il_wb, SL[3], NB, DM, DM, DM, DM, il_b, 1.f, nullptr, nullptr, 1, 0); launch(b); }
    // J2: wv = t0@wv^T -> SL0 (N=512) ; x1 = conv1(im0) -> SL1 (N=384)
    { JB b{}; b.add(SL[2], sda_wvb, SL[0], NB, 512, DM, DM, DM, sda_bv, 1.f, nullptr, nullptr, 0, 0);
              b.add(SL[3], w1c,     SL[1], NB, 384, DM, DM, DM, fda_b1, bnscale, bn1_g, bn1_b, 1, 0); launch(b); }
    // J3: t1 = wv@wo^T -> SL4 (K=512)
    { JB b{}; b.add(SL[0], sda_wob, SL[4], NB, DM, 512, 512, 512, sda_bo, 1.f, nullptr, nullptr, 0, 0); launch(b); }
    // fused FDA tail (in place on SL1)
    fda_fused_k<<<dim3(NB), dim3(128), 0, stream>>>(SL[1], ca_w1, ca_w2, sac, sa_b, dec_w, dec_b, sigma);
    // J4: im1 = gelu((x4@wf^T + bf)*bn2) -> SL5 (K=384)
    { JB b{}; b.add(SL[1], fda_wfb, SL[5], NB, DM, 384, 384, 384, fda_bf, bnscale, bn2_g, bn2_b, 1, 0); launch(b); }

    // J5: QKV both directions (6 jobs)
    { JB b{};
      b.add(SL[4], dmi_wqb, SL[0], NB, DM, DM, DM, DM, dmi_bq, 1.f, nullptr, nullptr, 0, 0);
      b.add(SL[5], dmi_wkb, SL[1], NB, DM, DM, DM, DM, dmi_bk, 1.f, nullptr, nullptr, 0, 0);
      b.add(SL[5], dmi_wvb, SL[2], NB, DM, DM, DM, DM, dmi_bv, 1.f, nullptr, nullptr, 0, 1);
      b.add(SL[5], dmi_wqb, SL[3], NB, DM, DM, DM, DM, dmi_bq, 1.f, nullptr, nullptr, 0, 0);
      b.add(SL[4], dmi_wkb, SL[6], NB, DM, DM, DM, DM, dmi_bk, 1.f, nullptr, nullptr, 0, 0);
      b.add(SL[4], dmi_wvb, SL[7], NB, DM, DM, DM, DM, dmi_bv, 1.f, nullptr, nullptr, 0, 1);
      launch(b); }
    // J6: scores (2 jobs, 2048 blocks)
    { JB b{}; b.add(SL[0], SL[1], SC1, NB, NB, DM, DM, DM, nullptr, iscale, nullptr, nullptr, 0, 0);
              b.add(SL[3], SL[6], SC2, NB, NB, DM, DM, DM, nullptr, iscale, nullptr, nullptr, 0, 0); launch(b); }
    softmax_rows_k<<<dim3(2 * NB), blk, 0, stream>>>(SC1);   // SC2 contiguous
    // J7: PV split-K=2 x 2 dirs (4 jobs, 768 blocks)
    { JB b{};
      b.add(SC1,        SL[2],        SL[0], NB, DM, 2048, NB, NB, nullptr, 1.f, nullptr, nullptr, 0, 0);
      b.add(SC1 + 2048, SL[2] + 2048, SL[1], NB, DM, 2048, NB, NB, nullptr, 1.f, nullptr, nullptr, 0, 0);
      b.add(SC2,        SL[7],        SL[3], NB, DM, 2048, NB, NB, nullptr, 1.f, nullptr, nullptr, 0, 0);
      b.add(SC2 + 2048, SL[7] + 2048, SL[6], NB, DM, 2048, NB, NB, nullptr, 1.f, nullptr, nullptr, 0, 0);
      launch(b); }
    reduce2_k<<<dim3((int)(SLOT / 2048)), blk, 0, stream>>>(SL[0], SL[1], SL[4], SL[3], SL[6], SL[5]);
    // J8/J9: gates
    { JB b{}; b.add(SL[4], tg_w1b, SL[0], NB, DM, DM, DM, DM, tg_b1, 1.f, nullptr, nullptr, 3, 0);
              b.add(SL[5], ig_w1b, SL[1], NB, DM, DM, DM, DM, ig_b1, 1.f, nullptr, nullptr, 3, 0); launch(b); }
    { JB b{}; b.add(SL[0], tg_w2b, SL[3], NB, DM, DM, DM, DM, tg_b2, 1.f, nullptr, nullptr, 2, 0);
              b.add(SL[1], ig_w2b, SL[6], NB, DM, DM, DM, DM, ig_b2, 1.f, nullptr, nullptr, 2, 0); launch(b); }
    combine2_k<<<dim3((NB * DM + 255) / 256), blk, 0, stream>>>(SL[2], SL[3], SL[4], t_scale, SL[6], SL[5], i_scale);
    cls_softmax_k<<<dim3(NB), dim3(64), 0, stream>>>(SL[2], cls_w, cls_b, out);
}